// Round 15
// baseline (1313.685 us; speedup 1.0000x reference)
//
#include <hip/hip_runtime.h>
#include <cfloat>

#define THREADS 256

// Force a value to stay in a VGPR (no rematerialization past this point).
#define PIN(x) asm volatile("" : "+v"(x))

__device__ __forceinline__ float lrelu01(float v){ return v > 0.f ? v : 0.01f * v; }
__device__ __forceinline__ float reluf(float v){ return v > 0.f ? v : 0.f; }
__device__ __forceinline__ float sigmf(float v){ return 1.f / (1.f + __expf(-v)); }
__device__ __forceinline__ float tanhfast(float v){
    float t = __expf(-2.f * fabsf(v));
    float r = (1.f - t) / (1.f + t);
    return v < 0.f ? -r : r;
}
__device__ __forceinline__ float eluf(float v){ return v > 0.f ? v : __expf(v) - 1.f; }
__device__ __forceinline__ float wmaxf(float v){
    #pragma unroll
    for (int o = 32; o > 0; o >>= 1) v = fmaxf(v, __shfl_xor(v, o, 64));
    return v;
}
__device__ __forceinline__ float wsumf(float v){
    #pragma unroll
    for (int o = 32; o > 0; o >>= 1) v += __shfl_xor(v, o, 64);
    return v;
}

template<int ACT>
__device__ __forceinline__ float actf(float v){
    if (ACT == 1) return lrelu01(v);
    if (ACT == 2) return reluf(v);
    return v;
}

// Stage up to 64 rows (4096 floats) into LDS via async global->LDS DMA (256 thr).
__device__ __forceinline__ void stage_tile(const float* __restrict__ src, float* lds,
                                           int tid, int validf4){
    #pragma unroll
    for (int j = 0; j < 4; ++j){
        int idx = tid + j * 256;
        if (idx < validf4){
            __builtin_amdgcn_global_load_lds(
                (const __attribute__((address_space(1))) void*)(src + (size_t)idx * 4),
                (__attribute__((address_space(3))) void*)(lds + (size_t)idx * 4),
                16, 0, 0);
        }
    }
}

// ---------------- CSR build ----------------
__global__ void k_hist(const int* __restrict__ dst, int* __restrict__ cnt, int E){
    int e = blockIdx.x * blockDim.x + threadIdx.x;
    if (e < E) atomicAdd(&cnt[dst[e]], 1);
}

__global__ void k_scan1(const int* __restrict__ cnt, int* __restrict__ rowptr,
                        int* __restrict__ bsum, int N){
    const int tid = threadIdx.x;
    int i = blockIdx.x * 1024 + tid;
    int v = (i < N) ? cnt[i] : 0;
    int lane = tid & 63, wv = tid >> 6;
    int s = v;
    #pragma unroll
    for (int o = 1; o < 64; o <<= 1){
        int u = __shfl_up(s, o, 64);
        if (lane >= o) s += u;
    }
    __shared__ int wsum[16];
    if (lane == 63) wsum[wv] = s;
    __syncthreads();
    if (wv == 0 && lane < 16){
        int ws = wsum[lane];
        #pragma unroll
        for (int o = 1; o < 16; o <<= 1){
            int u = __shfl_up(ws, o, 64);
            if (lane >= o) ws += u;
        }
        wsum[lane] = ws;
    }
    __syncthreads();
    int woff = wv ? wsum[wv - 1] : 0;
    int incl = s + woff;
    if (i < N) rowptr[i] = incl - v;
    if (tid == 1023) bsum[blockIdx.x] = incl;
}

__global__ void k_scan2(int* __restrict__ bsum, int* __restrict__ rowptr, int NB, int N){
    const int tid = threadIdx.x;
    int v = (tid < NB) ? bsum[tid] : 0;
    int lane = tid & 63, wv = tid >> 6;
    int s = v;
    #pragma unroll
    for (int o = 1; o < 64; o <<= 1){
        int u = __shfl_up(s, o, 64);
        if (lane >= o) s += u;
    }
    __shared__ int wsum[16];
    if (lane == 63) wsum[wv] = s;
    __syncthreads();
    if (wv == 0 && lane < 16){
        int ws = wsum[lane];
        #pragma unroll
        for (int o = 1; o < 16; o <<= 1){
            int u = __shfl_up(ws, o, 64);
            if (lane >= o) ws += u;
        }
        wsum[lane] = ws;
    }
    __syncthreads();
    int woff = wv ? wsum[wv - 1] : 0;
    int incl = s + woff;
    if (tid < NB) bsum[tid] = incl - v;
    if (tid == 1023) rowptr[N] = incl;
}

__global__ void k_scan3(int* __restrict__ rowptr, const int* __restrict__ bsum, int N){
    int i = blockIdx.x * 1024 + threadIdx.x;
    if (i < N) rowptr[i] += bsum[blockIdx.x];
}

// scatter: CSR-ordered src (srcC) + edge->slot mapping (for CSR-ordered logits)
__global__ void k_scatter(const int* __restrict__ dst, const int* __restrict__ srcv,
                          const int* __restrict__ rowptr, int* __restrict__ cnt2,
                          int* __restrict__ srcC, int* __restrict__ slot, int E){
    int e = blockIdx.x * blockDim.x + threadIdx.x;
    if (e < E){
        int d = dst[e];
        int p = rowptr[d] + atomicAdd(&cnt2[d], 1);
        srcC[p] = srcv[e];
        slot[e] = p;
    }
}

__global__ void k_browptr(const int* __restrict__ batch, int* __restrict__ rp, int N, int B){
    int n = blockIdx.x * blockDim.x + threadIdx.x;
    if (n >= N) return;
    int b = batch[n];
    int bp = (n == 0) ? -1 : batch[n - 1];
    for (int g = bp + 1; g <= b; ++g) rp[g] = n;
    if (n == N - 1){ for (int g = b + 1; g <= B; ++g) rp[g] = N; }
}

// ---------- LDS-staged 64-col GEMM (single output) ----------
template<int ACT, int NDOT>
__global__ __launch_bounds__(THREADS, 2)
void k_mm64t(const float* __restrict__ in, const float* __restrict__ W, int ldw,
             const float* __restrict__ bias, float* __restrict__ out,
             const float* __restrict__ v0, const float* __restrict__ v1,
             float* __restrict__ o0, float* __restrict__ o1, int rows){
    __shared__ float tile[2][4096];
    const int tid  = threadIdx.x;
    const int lane = tid & 63;
    const int wv   = tid >> 6;
    float w[64];
    #pragma unroll
    for (int k = 0; k < 64; k += 4){
        float4 t4 = *(const float4*)(W + (size_t)lane * ldw + k);
        w[k] = t4.x; w[k+1] = t4.y; w[k+2] = t4.z; w[k+3] = t4.w;
    }
    #pragma unroll
    for (int k = 0; k < 64; ++k) PIN(w[k]);
    const float bb  = bias ? bias[lane] : 0.f;
    const float vl0 = (NDOT > 0) ? v0[lane] : 0.f;
    const float vl1 = (NDOT > 1) ? v1[lane] : 0.f;
    const int ntiles = (rows + 63) >> 6;
    const int totf4  = rows * 16;
    int t = blockIdx.x;
    if (t >= ntiles) return;
    stage_tile(in + (size_t)t * 4096, tile[0], tid, min(1024, totf4 - t * 1024));
    __syncthreads();
    int b = 0;
    while (t < ntiles){
        int tn = t + gridDim.x;
        if (tn < ntiles)
            stage_tile(in + (size_t)tn * 4096, tile[b ^ 1], tid, min(1024, totf4 - tn * 1024));
        #pragma unroll 4
        for (int r = 0; r < 16; ++r){
            int row = wv * 16 + r;
            int g = t * 64 + row;
            const float4* rp = (const float4*)&tile[b][row * 64];
            float a0 = bb, a1 = 0.f, a2 = 0.f, a3 = 0.f;
            #pragma unroll
            for (int kk = 0; kk < 16; ++kk){
                float4 q = rp[kk];
                a0 = fmaf(q.x, w[kk*4],   a0);
                a1 = fmaf(q.y, w[kk*4+1], a1);
                a2 = fmaf(q.z, w[kk*4+2], a2);
                a3 = fmaf(q.w, w[kk*4+3], a3);
            }
            float v = actf<ACT>((a0 + a1) + (a2 + a3));
            if (g < rows){
                out[(size_t)g * 64 + lane] = v;
                if (NDOT > 0){
                    float s0 = wsumf(v * vl0);
                    float s1 = (NDOT > 1) ? wsumf(v * vl1) : 0.f;
                    if (lane == 0){ o0[g] = s0; if (NDOT > 1) o1[g] = s1; }
                }
            }
        }
        __syncthreads();
        b ^= 1; t = tn;
    }
}

// ---------- Dual GEMM: 128 weights/lane, each row-read serves BOTH outputs ----------
__global__ __launch_bounds__(THREADS, 2)
void k_mm64_x2(const float* __restrict__ in,
               const float* __restrict__ W0, int ldw0,
               const float* __restrict__ W1, int ldw1,
               float* __restrict__ out0, float* __restrict__ out1, int rows){
    __shared__ float tile[2][4096];
    const int tid  = threadIdx.x;
    const int lane = tid & 63;
    const int wv   = tid >> 6;
    float w0[64], w1[64];
    #pragma unroll
    for (int k = 0; k < 64; k += 4){
        float4 a = *(const float4*)(W0 + (size_t)lane * ldw0 + k);
        w0[k] = a.x; w0[k+1] = a.y; w0[k+2] = a.z; w0[k+3] = a.w;
        float4 b4 = *(const float4*)(W1 + (size_t)lane * ldw1 + k);
        w1[k] = b4.x; w1[k+1] = b4.y; w1[k+2] = b4.z; w1[k+3] = b4.w;
    }
    #pragma unroll
    for (int k = 0; k < 64; ++k){ PIN(w0[k]); PIN(w1[k]); }
    const int ntiles = (rows + 63) >> 6;
    const int totf4  = rows * 16;
    int t = blockIdx.x;
    if (t >= ntiles) return;
    stage_tile(in + (size_t)t * 4096, tile[0], tid, min(1024, totf4 - t * 1024));
    __syncthreads();
    int b = 0;
    while (t < ntiles){
        int tn = t + gridDim.x;
        if (tn < ntiles)
            stage_tile(in + (size_t)tn * 4096, tile[b ^ 1], tid, min(1024, totf4 - tn * 1024));
        #pragma unroll 2
        for (int r = 0; r < 16; ++r){
            int row = wv * 16 + r;
            int g = t * 64 + row;
            const float4* rp = (const float4*)&tile[b][row * 64];
            float a0 = 0.f, a1 = 0.f, c0 = 0.f, c1 = 0.f;
            #pragma unroll
            for (int kk = 0; kk < 16; ++kk){
                float4 q = rp[kk];
                a0 = fmaf(q.x, w0[kk*4],   a0);
                a1 = fmaf(q.y, w0[kk*4+1], a1);
                a0 = fmaf(q.z, w0[kk*4+2], a0);
                a1 = fmaf(q.w, w0[kk*4+3], a1);
                c0 = fmaf(q.x, w1[kk*4],   c0);
                c1 = fmaf(q.y, w1[kk*4+1], c1);
                c0 = fmaf(q.z, w1[kk*4+2], c0);
                c1 = fmaf(q.w, w1[kk*4+3], c1);
            }
            if (g < rows){
                out0[(size_t)g * 64 + lane] = a0 + a1;
                out1[(size_t)g * 64 + lane] = c0 + c1;
            }
        }
        __syncthreads();
        b ^= 1; t = tn;
    }
}

// ---------- GRU stage A: all 3 Wx gates per wave, 2-row interleaved ----------
__global__ __launch_bounds__(THREADS, 2)
void k_gru_wx3(const float* __restrict__ xin, const float* __restrict__ wx,
               const float* __restrict__ bx,
               float* __restrict__ Tr, float* __restrict__ Tz, float* __restrict__ Tn,
               int rows){
    __shared__ float tile[2][4096];
    const int tid  = threadIdx.x;
    const int lane = tid & 63;
    const int wv   = tid >> 6;
    float wr[64], wz[64], wn[64];
    #pragma unroll
    for (int k = 0; k < 64; k += 4){
        float4 a = *(const float4*)(wx + (size_t)lane * 64 + k);
        wr[k] = a.x; wr[k+1] = a.y; wr[k+2] = a.z; wr[k+3] = a.w;
        float4 b4 = *(const float4*)(wx + (size_t)(64 + lane) * 64 + k);
        wz[k] = b4.x; wz[k+1] = b4.y; wz[k+2] = b4.z; wz[k+3] = b4.w;
        float4 c4 = *(const float4*)(wx + (size_t)(128 + lane) * 64 + k);
        wn[k] = c4.x; wn[k+1] = c4.y; wn[k+2] = c4.z; wn[k+3] = c4.w;
    }
    #pragma unroll
    for (int k = 0; k < 64; ++k){ PIN(wr[k]); PIN(wz[k]); PIN(wn[k]); }
    const float br = bx[lane], bz = bx[64 + lane], bn = bx[128 + lane];
    const int ntiles = (rows + 63) >> 6;
    const int totf4  = rows * 16;
    int t = blockIdx.x;
    if (t >= ntiles) return;
    stage_tile(xin + (size_t)t * 4096, tile[0], tid, min(1024, totf4 - t * 1024));
    __syncthreads();
    int b = 0;
    while (t < ntiles){
        int tn = t + gridDim.x;
        if (tn < ntiles)
            stage_tile(xin + (size_t)tn * 4096, tile[b ^ 1], tid, min(1024, totf4 - tn * 1024));
        #pragma unroll 1
        for (int r = 0; r < 16; r += 2){
            int rowA = wv * 16 + r;
            int gA = t * 64 + rowA, gB = gA + 1;
            const float4* rpA = (const float4*)&tile[b][rowA * 64];
            const float4* rpB = (const float4*)&tile[b][(rowA + 1) * 64];
            float rA = br, zA = bz, nA = bn;
            float rB = br, zB = bz, nB = bn;
            #pragma unroll
            for (int kk = 0; kk < 16; ++kk){
                float4 qA = rpA[kk];
                float4 qB = rpB[kk];
                rA = fmaf(qA.x, wr[kk*4],   rA);
                rB = fmaf(qB.x, wr[kk*4],   rB);
                zA = fmaf(qA.x, wz[kk*4],   zA);
                zB = fmaf(qB.x, wz[kk*4],   zB);
                nA = fmaf(qA.x, wn[kk*4],   nA);
                nB = fmaf(qB.x, wn[kk*4],   nB);
                rA = fmaf(qA.y, wr[kk*4+1], rA);
                rB = fmaf(qB.y, wr[kk*4+1], rB);
                zA = fmaf(qA.y, wz[kk*4+1], zA);
                zB = fmaf(qB.y, wz[kk*4+1], zB);
                nA = fmaf(qA.y, wn[kk*4+1], nA);
                nB = fmaf(qB.y, wn[kk*4+1], nB);
                rA = fmaf(qA.z, wr[kk*4+2], rA);
                rB = fmaf(qB.z, wr[kk*4+2], rB);
                zA = fmaf(qA.z, wz[kk*4+2], zA);
                zB = fmaf(qB.z, wz[kk*4+2], zB);
                nA = fmaf(qA.z, wn[kk*4+2], nA);
                nB = fmaf(qB.z, wn[kk*4+2], nB);
                rA = fmaf(qA.w, wr[kk*4+3], rA);
                rB = fmaf(qB.w, wr[kk*4+3], rB);
                zA = fmaf(qA.w, wz[kk*4+3], zA);
                zB = fmaf(qB.w, wz[kk*4+3], zB);
                nA = fmaf(qA.w, wn[kk*4+3], nA);
                nB = fmaf(qB.w, wn[kk*4+3], nB);
            }
            if (gA < rows){
                size_t ia = (size_t)gA * 64 + lane;
                Tr[ia] = rA; Tz[ia] = zA; Tn[ia] = nA;
            }
            if (gB < rows){
                size_t ib = (size_t)gB * 64 + lane;
                Tr[ib] = rB; Tz[ib] = zB; Tn[ib] = nB;
            }
        }
        __syncthreads();
        b ^= 1; t = tn;
    }
}

// ---------- GRU stage B: all 3 Wh gates per wave + in-register combine, 2-row ----------
__global__ __launch_bounds__(THREADS, 2)
void k_gru_whf(const float* __restrict__ xp, const float* __restrict__ wh,
               const float* __restrict__ bh,
               const float* __restrict__ Tr, const float* __restrict__ Tz,
               const float* __restrict__ Tn, float* __restrict__ out, int rows){
    __shared__ float tile[2][4096];
    const int tid  = threadIdx.x;
    const int lane = tid & 63;
    const int wv   = tid >> 6;
    float wr[64], wz[64], wn[64];
    #pragma unroll
    for (int k = 0; k < 64; k += 4){
        float4 a = *(const float4*)(wh + (size_t)lane * 64 + k);
        wr[k] = a.x; wr[k+1] = a.y; wr[k+2] = a.z; wr[k+3] = a.w;
        float4 b4 = *(const float4*)(wh + (size_t)(64 + lane) * 64 + k);
        wz[k] = b4.x; wz[k+1] = b4.y; wz[k+2] = b4.z; wz[k+3] = b4.w;
        float4 c4 = *(const float4*)(wh + (size_t)(128 + lane) * 64 + k);
        wn[k] = c4.x; wn[k+1] = c4.y; wn[k+2] = c4.z; wn[k+3] = c4.w;
    }
    #pragma unroll
    for (int k = 0; k < 64; ++k){ PIN(wr[k]); PIN(wz[k]); PIN(wn[k]); }
    const float br = bh[lane], bz = bh[64 + lane], bn = bh[128 + lane];
    const int ntiles = (rows + 63) >> 6;
    const int totf4  = rows * 16;
    int t = blockIdx.x;
    if (t >= ntiles) return;
    stage_tile(xp + (size_t)t * 4096, tile[0], tid, min(1024, totf4 - t * 1024));
    __syncthreads();
    int b = 0;
    while (t < ntiles){
        int tn = t + gridDim.x;
        if (tn < ntiles)
            stage_tile(xp + (size_t)tn * 4096, tile[b ^ 1], tid, min(1024, totf4 - tn * 1024));
        #pragma unroll 1
        for (int r = 0; r < 16; r += 2){
            int rowA = wv * 16 + r;
            int gA = t * 64 + rowA, gB = gA + 1;
            bool okA = gA < rows, okB = gB < rows;
            size_t ia = (size_t)gA * 64 + lane;
            size_t ib = (size_t)gB * 64 + lane;
            // early-issue both rows' T loads; consumed after ~770 cyc of FMA
            float trA = 0.f, tzA = 0.f, tnA = 0.f, trB = 0.f, tzB = 0.f, tnB = 0.f;
            if (okA){ trA = Tr[ia]; tzA = Tz[ia]; tnA = Tn[ia]; }
            if (okB){ trB = Tr[ib]; tzB = Tz[ib]; tnB = Tn[ib]; }
            const float4* rpA = (const float4*)&tile[b][rowA * 64];
            const float4* rpB = (const float4*)&tile[b][(rowA + 1) * 64];
            float xpA = tile[b][rowA * 64 + lane];
            float xpB = tile[b][(rowA + 1) * 64 + lane];
            float rA = br, zA = bz, nA = bn;
            float rB = br, zB = bz, nB = bn;
            #pragma unroll
            for (int kk = 0; kk < 16; ++kk){
                float4 qA = rpA[kk];
                float4 qB = rpB[kk];
                rA = fmaf(qA.x, wr[kk*4],   rA);
                rB = fmaf(qB.x, wr[kk*4],   rB);
                zA = fmaf(qA.x, wz[kk*4],   zA);
                zB = fmaf(qB.x, wz[kk*4],   zB);
                nA = fmaf(qA.x, wn[kk*4],   nA);
                nB = fmaf(qB.x, wn[kk*4],   nB);
                rA = fmaf(qA.y, wr[kk*4+1], rA);
                rB = fmaf(qB.y, wr[kk*4+1], rB);
                zA = fmaf(qA.y, wz[kk*4+1], zA);
                zB = fmaf(qB.y, wz[kk*4+1], zB);
                nA = fmaf(qA.y, wn[kk*4+1], nA);
                nB = fmaf(qB.y, wn[kk*4+1], nB);
                rA = fmaf(qA.z, wr[kk*4+2], rA);
                rB = fmaf(qB.z, wr[kk*4+2], rB);
                zA = fmaf(qA.z, wz[kk*4+2], zA);
                zB = fmaf(qB.z, wz[kk*4+2], zB);
                nA = fmaf(qA.z, wn[kk*4+2], nA);
                nB = fmaf(qB.z, wn[kk*4+2], nB);
                rA = fmaf(qA.w, wr[kk*4+3], rA);
                rB = fmaf(qB.w, wr[kk*4+3], rB);
                zA = fmaf(qA.w, wz[kk*4+3], zA);
                zB = fmaf(qB.w, wz[kk*4+3], zB);
                nA = fmaf(qA.w, wn[kk*4+3], nA);
                nB = fmaf(qB.w, wn[kk*4+3], nB);
            }
            if (okA){
                float r_ = sigmf(trA + rA);
                float z_ = sigmf(tzA + zA);
                float nn = tanhfast(fmaf(r_, nA, tnA));
                out[ia] = reluf((1.f - z_) * nn + z_ * xpA);
            }
            if (okB){
                float r_ = sigmf(trB + rB);
                float z_ = sigmf(tzB + zB);
                float nn = tanhfast(fmaf(r_, nB, tnB));
                out[ib] = reluf((1.f - z_) * nn + z_ * xpB);
            }
        }
        __syncthreads();
        b ^= 1; t = tn;
    }
}

// GATEConv per-edge logit -> CSR-ordered logitC[slot[e]] (thread-per-edge; at its
// gather-BW floor ~45-50us. Wave-per-edge variant was 3x SLOWER — R14 post-mortem.)
__global__ __launch_bounds__(THREADS, 3)
void k_gate_logit(const float* __restrict__ np1, const float* __restrict__ ea,
                  const float* __restrict__ w1,  // gate_lin1_w [64][80]
                  const float* __restrict__ attl, const float* __restrict__ nat,
                  const int* __restrict__ src, const int* __restrict__ dstv,
                  const int* __restrict__ slot, float* __restrict__ logitC, int E){
    __shared__ float wlds[16 * 64];
    __shared__ float al[64];
    for (int i = threadIdx.x; i < 1024; i += blockDim.x){
        int j = i >> 6, k = i & 63;
        wlds[i] = w1[k * 80 + 64 + j];
    }
    if (threadIdx.x < 64) al[threadIdx.x] = attl[threadIdx.x];
    __syncthreads();
    int e = blockIdx.x * blockDim.x + threadIdx.x;
    if (e >= E) return;
    int s = src[e], d = dstv[e];
    float acc[64];
    const float* nr = np1 + (size_t)s * 64;
    #pragma unroll
    for (int k = 0; k < 64; k += 4){
        float4 t = *(const float4*)(nr + k);
        acc[k] = t.x; acc[k+1] = t.y; acc[k+2] = t.z; acc[k+3] = t.w;
    }
    const float* er = ea + (size_t)e * 16;
    #pragma unroll
    for (int j = 0; j < 16; ++j){
        float v = er[j];
        #pragma unroll
        for (int k = 0; k < 64; k += 4){
            float4 t = *(const float4*)&wlds[j * 64 + k];
            acc[k]   = fmaf(v, t.x, acc[k]);
            acc[k+1] = fmaf(v, t.y, acc[k+1]);
            acc[k+2] = fmaf(v, t.z, acc[k+2]);
            acc[k+3] = fmaf(v, t.w, acc[k+3]);
        }
    }
    float l = 0.f;
    #pragma unroll
    for (int k = 0; k < 64; ++k) l = fmaf(lrelu01(acc[k]), al[k], l);
    logitC[slot[e]] = lrelu01(l + nat[d]);
}

// GATE aggregate: linear CSR reads, 4-way unrolled row gathers
__global__ __launch_bounds__(THREADS, 8)
void k_gate_agg(const float* __restrict__ logitC, const int* __restrict__ srcC,
                const int* __restrict__ rowptr,
                const float* __restrict__ xg, const float* __restrict__ bias,
                float* __restrict__ xin, int N){
    const int lane = threadIdx.x & 63;
    const int d = blockIdx.x * (blockDim.x >> 6) + (threadIdx.x >> 6);
    if (d >= N) return;
    int r0 = rowptr[d], r1 = rowptr[d + 1];
    float m = -3.4e38f;
    for (int j = r0 + lane; j < r1; j += 64) m = fmaxf(m, logitC[j]);
    m = wmaxf(m);
    float s0 = 0.f, s1 = 0.f, s2 = 0.f, s3 = 0.f;
    float h0 = 0.f, h1 = 0.f, h2 = 0.f, h3 = 0.f;
    int j = r0;
    for (; j + 3 < r1; j += 4){
        float l0 = logitC[j], l1 = logitC[j+1], l2 = logitC[j+2], l3 = logitC[j+3];
        int n0 = srcC[j], n1 = srcC[j+1], n2 = srcC[j+2], n3 = srcC[j+3];
        float w0 = __expf(l0 - m), w1 = __expf(l1 - m);
        float w2 = __expf(l2 - m), w3 = __expf(l3 - m);
        s0 += w0; s1 += w1; s2 += w2; s3 += w3;
        h0 = fmaf(w0, xg[(size_t)n0 * 64 + lane], h0);
        h1 = fmaf(w1, xg[(size_t)n1 * 64 + lane], h1);
        h2 = fmaf(w2, xg[(size_t)n2 * 64 + lane], h2);
        h3 = fmaf(w3, xg[(size_t)n3 * 64 + lane], h3);
    }
    for (; j < r1; ++j){
        float w0 = __expf(logitC[j] - m);
        s0 += w0;
        h0 = fmaf(w0, xg[(size_t)srcC[j] * 64 + lane], h0);
    }
    float s = (s0 + s1) + (s2 + s3);
    float hk = (h0 + h1) + (h2 + h3);
    float h = hk / (s + 1e-16f) + bias[lane];
    xin[(size_t)d * 64 + lane] = eluf(h);
}

// GAT aggregate: logits inline from asrc[srcC[j]]+adst[d], 4-way unrolled
__global__ __launch_bounds__(THREADS, 8)
void k_atom_agg(const float* __restrict__ asrc, const float* __restrict__ adst,
                const int* __restrict__ srcC, const int* __restrict__ rowptr,
                const float* __restrict__ xl,
                const float* __restrict__ bias, float* __restrict__ xin, int N){
    const int lane = threadIdx.x & 63;
    const int d = blockIdx.x * (blockDim.x >> 6) + (threadIdx.x >> 6);
    if (d >= N) return;
    int r0 = rowptr[d], r1 = rowptr[d + 1];
    const float ad = adst[d];
    float m = -3.4e38f;
    for (int j = r0 + lane; j < r1; j += 64)
        m = fmaxf(m, lrelu01(asrc[srcC[j]] + ad));
    m = wmaxf(m);
    float s0 = 0.f, s1 = 0.f, s2 = 0.f, s3 = 0.f;
    float h0 = 0.f, h1 = 0.f, h2 = 0.f, h3 = 0.f;
    int j = r0;
    for (; j + 3 < r1; j += 4){
        int n0 = srcC[j], n1 = srcC[j+1], n2 = srcC[j+2], n3 = srcC[j+3];
        float w0 = __expf(lrelu01(asrc[n0] + ad) - m);
        float w1 = __expf(lrelu01(asrc[n1] + ad) - m);
        float w2 = __expf(lrelu01(asrc[n2] + ad) - m);
        float w3 = __expf(lrelu01(asrc[n3] + ad) - m);
        s0 += w0; s1 += w1; s2 += w2; s3 += w3;
        h0 = fmaf(w0, xl[(size_t)n0 * 64 + lane], h0);
        h1 = fmaf(w1, xl[(size_t)n1 * 64 + lane], h1);
        h2 = fmaf(w2, xl[(size_t)n2 * 64 + lane], h2);
        h3 = fmaf(w3, xl[(size_t)n3 * 64 + lane], h3);
    }
    for (; j < r1; ++j){
        int n0 = srcC[j];
        float w0 = __expf(lrelu01(asrc[n0] + ad) - m);
        s0 += w0;
        h0 = fmaf(w0, xl[(size_t)n0 * 64 + lane], h0);
    }
    float s = (s0 + s1) + (s2 + s3);
    float hk = (h0 + h1) + (h2 + h3);
    float h = hk / (s + 1e-16f) + bias[lane];
    xin[(size_t)d * 64 + lane] = eluf(h);
}

// out0[b] = relu(sum over nodes of graph b)
__global__ __launch_bounds__(THREADS, 4)
void k_out0(const float* __restrict__ x, const int* __restrict__ rpB,
            float* __restrict__ outB, int B){
    const int lane = threadIdx.x & 63;
    const int b = blockIdx.x * (blockDim.x >> 6) + (threadIdx.x >> 6);
    if (b >= B) return;
    int r0 = rpB[b], r1 = rpB[b + 1];
    float a = 0.f;
    for (int n = r0; n < r1; ++n) a += x[(size_t)n * 64 + lane];
    outB[(size_t)b * 64 + lane] = reluf(a);
}

// readout attention step
__global__ __launch_bounds__(THREADS, 2)
void k_mol_attn(const float* __restrict__ outB, const float* __restrict__ W,
                const float* __restrict__ attdst, const float* __restrict__ a_src,
                const float* __restrict__ xs, const int* __restrict__ rpB,
                const float* __restrict__ bias, float* __restrict__ hB, int B){
    const int lane = threadIdx.x & 63;
    const int b = blockIdx.x * (blockDim.x >> 6) + (threadIdx.x >> 6);
    if (b >= B) return;
    float w[64];
    #pragma unroll
    for (int k = 0; k < 64; k += 4){
        float4 t = *(const float4*)(W + (size_t)lane * 64 + k);
        w[k] = t.x; w[k+1] = t.y; w[k+2] = t.z; w[k+3] = t.w;
    }
    const float* orow = outB + (size_t)b * 64;
    float acc = 0.f;
    #pragma unroll
    for (int k = 0; k < 64; ++k) acc = fmaf(orow[k], w[k], acc);
    float g = wsumf(acc * attdst[lane]);
    int r0 = rpB[b], r1 = rpB[b + 1];
    float m = -3.4e38f;
    for (int n = r0 + lane; n < r1; n += 64) m = fmaxf(m, lrelu01(a_src[n] + g));
    m = wmaxf(m);
    float s = 0.f, hk = 0.f;
    for (int n = r0; n < r1; ++n){
        float l = lrelu01(a_src[n] + g);
        float ww = __expf(l - m);
        s += ww;
        hk = fmaf(ww, xs[(size_t)n * 64 + lane], hk);
    }
    hB[(size_t)b * 64 + lane] = eluf(hk / (s + 1e-16f) + bias[lane]);
}

// regression head
__global__ void k_head(const float* __restrict__ emb, const float* __restrict__ lng,
                       const float* __restrict__ lnb,
                       const float* __restrict__ w1, const float* __restrict__ b1,
                       const float* __restrict__ w2, const float* __restrict__ b2,
                       const float* __restrict__ w3, const float* __restrict__ b3,
                       float* __restrict__ out, int B, int P){
    __shared__ float w1t[4096], w2t[4096];
    __shared__ float buf0[4][64], buf1[4][64];
    for (int i = threadIdx.x; i < 4096; i += blockDim.x){
        int h = i >> 6, k = i & 63;
        w1t[k * 64 + h] = w1[i];
        w2t[k * 64 + h] = w2[i];
    }
    __syncthreads();
    const int lane = threadIdx.x & 63;
    const int wv = threadIdx.x >> 6;
    int b = blockIdx.x * (blockDim.x >> 6) + wv;
    bool act = b < B;
    float v = act ? emb[(size_t)b * 64 + lane] : 0.f;
    float mean = wsumf(v) * 0.015625f;
    float dv = v - mean;
    float var = wsumf(dv * dv) * 0.015625f;
    float y = dv * rsqrtf(var + 1e-5f) * lng[lane] + lnb[lane];
    buf0[wv][lane] = y;
    __syncthreads();
    float a1 = b1[lane];
    #pragma unroll
    for (int k = 0; k < 64; ++k) a1 = fmaf(buf0[wv][k], w1t[k * 64 + lane], a1);
    float y1 = reluf(a1);
    buf1[wv][lane] = y1;
    __syncthreads();
    float a2 = b2[lane];
    #pragma unroll
    for (int k = 0; k < 64; ++k) a2 = fmaf(buf1[wv][k], w2t[k * 64 + lane], a2);
    float y2 = reluf(a2);
    for (int p = 0; p < P; ++p){
        float s = wsumf(y2 * w3[p * 64 + lane]);
        if (lane == 0 && act) out[(size_t)b * P + p] = s + b3[p];
    }
}

extern "C" void kernel_launch(void* const* d_in, const int* in_sizes, int n_in,
                              void* d_out, int out_size, void* d_ws, size_t ws_size,
                              hipStream_t stream){
    const float* x       = (const float*)d_in[0];
    const float* eattr   = (const float*)d_in[1];
    const float* lin1_w  = (const float*)d_in[2];
    const float* lin1_b  = (const float*)d_in[3];
    const float* g_l1w   = (const float*)d_in[4];
    const float* g_l2w   = (const float*)d_in[5];
    const float* g_attl  = (const float*)d_in[6];
    const float* g_attr  = (const float*)d_in[7];
    const float* g_bias  = (const float*)d_in[8];
    const float* gru0_wx = (const float*)d_in[9];
    const float* gru0_wh = (const float*)d_in[10];
    const float* gru0_bx = (const float*)d_in[11];
    const float* gru0_bh = (const float*)d_in[12];
    const float* a_linw  = (const float*)d_in[13];
    const float* a_asrc  = (const float*)d_in[14];
    const float* a_adst  = (const float*)d_in[15];
    const float* a_bias  = (const float*)d_in[16];
    const float* a_gwx   = (const float*)d_in[17];
    const float* a_gwh   = (const float*)d_in[18];
    const float* a_gbx   = (const float*)d_in[19];
    const float* a_gbh   = (const float*)d_in[20];
    const float* m_linw  = (const float*)d_in[21];
    const float* m_asrcv = (const float*)d_in[22];
    const float* m_adstv = (const float*)d_in[23];
    const float* m_bias  = (const float*)d_in[24];
    const float* m_gwx   = (const float*)d_in[25];
    const float* m_gwh   = (const float*)d_in[26];
    const float* m_gbx   = (const float*)d_in[27];
    const float* m_gbh   = (const float*)d_in[28];
    const float* lin2_w  = (const float*)d_in[29];
    const float* lin2_b  = (const float*)d_in[30];
    const float* ln_g    = (const float*)d_in[31];
    const float* ln_b    = (const float*)d_in[32];
    const float* h1_w    = (const float*)d_in[33];
    const float* h1_b    = (const float*)d_in[34];
    const float* h2_w    = (const float*)d_in[35];
    const float* h2_b    = (const float*)d_in[36];
    const float* h3_w    = (const float*)d_in[37];
    const float* h3_b    = (const float*)d_in[38];
    const int*   ei      = (const int*)d_in[39];
    const int*   batch   = (const int*)d_in[40];
    float* out = (float*)d_out;

    const int N = in_sizes[0] / 64;
    const int E = in_sizes[1] / 16;
    const int P = in_sizes[38];
    const int B = out_size / (P > 0 ? P : 1);
    const int* srcv = ei;
    const int* dstv = ei + E;

    // ---- workspace layout ----
    float* Wb = (float*)d_ws;
    size_t nb = (size_t)N * 64;
    size_t bb = (size_t)B * 64;
    float* P0 = Wb;
    float* P1 = P0 + nb;
    float* P2 = P1 + nb;
    float* P3 = P2 + nb;
    float* P4 = P3 + nb;
    float* P5 = P4 + nb;
    float* logitC = P5 + nb;
    float* scal  = logitC + E;
    float* outB0 = scal + 2 * (size_t)N;
    float* outB1 = outB0 + bb;
    float* hB    = outB1 + bb;
    float* RB    = hB + bb;
    float* ZB    = RB + bb;
    float* XNB   = ZB + bb;
    int* srcC   = (int*)(XNB + bb);
    int* slot   = srcC + E;
    int* rowptr = slot + E;
    int* cnt    = rowptr + (N + 1);
    int* cnt2   = cnt + N;
    int* rpB    = cnt2 + N;
    int* bsum   = rpB + (B + 1);
    const int NB = (N + 1023) >> 10;
    size_t need = (size_t)((char*)(bsum + NB) - (char*)d_ws);
    if (need > ws_size) return;
    float* embB = XNB;

    dim3 blk(THREADS);
    int gE    = (E + THREADS - 1) / THREADS;
    int gN4   = (N + 3) / 4;
    int gB4   = (B + 3) / 4;
    int gN256 = (N + THREADS - 1) / THREADS;
    int ntN   = (N + 63) >> 6;
    int ntB   = (B + 63) >> 6;
    int GT_N  = ntN < 768 ? ntN : 768;   // 3 blocks/CU tile kernels
    int GT_N2 = ntN < 512 ? ntN : 512;   // 2 blocks/CU (high-VGPR fused kernels)
    int GT_B  = ntB;

    // ---- CSR build ----
    hipMemsetAsync(cnt, 0, sizeof(int) * 2 * (size_t)N, stream);
    k_hist<<<gE, blk, 0, stream>>>(dstv, cnt, E);
    k_scan1<<<NB, 1024, 0, stream>>>(cnt, rowptr, bsum, N);
    k_scan2<<<1, 1024, 0, stream>>>(bsum, rowptr, NB, N);
    k_scan3<<<NB, 1024, 0, stream>>>(rowptr, bsum, N);
    k_scatter<<<gE, blk, 0, stream>>>(dstv, srcv, rowptr, cnt2, srcC, slot, E);
    k_browptr<<<gN256, blk, 0, stream>>>(batch, rpB, N, B);

    // ---- phase 0: x1 = lrelu(x@lin1+b) -> P0, fused nat -> scal ----
    k_mm64t<1,1><<<GT_N, blk, 0, stream>>>(x, lin1_w, 64, lin1_b, P0,
                                           g_attr, nullptr, scal, nullptr, N);

    // ---- GATEConv ----
    k_mm64_x2<<<GT_N2, blk, 0, stream>>>(P0, g_l1w, 80, g_l2w, 64, P1, P2, N); // np1, xg
    k_gate_logit<<<gE, blk, 0, stream>>>(P1, eattr, g_l1w, g_attl, scal, srcv, dstv,
                                         slot, logitC, E);
    k_gate_agg<<<gN4, blk, 0, stream>>>(logitC, srcC, rowptr, P2, g_bias, P3, N);
    // GRU0: xin=P3, xp=P0 -> x=P1. T: Tr=P2, Tz=P5, Tn=P4
    k_gru_wx3<<<GT_N2, blk, 0, stream>>>(P3, gru0_wx, gru0_bx, P2, P5, P4, N);
    k_gru_whf<<<GT_N2, blk, 0, stream>>>(P0, gru0_wh, gru0_bh, P2, P5, P4, P1, N);

    // ---- atom layer 0: x=P1 -> x=P4. T: Tr=P0, Tz=P2, Tn=P5 ----
    k_mm64t<0,2><<<GT_N, blk, 0, stream>>>(P1, a_linw, 64, nullptr, P0,
                                           a_asrc, a_adst, scal, scal + N, N);
    k_atom_agg<<<gN4, blk, 0, stream>>>(scal, scal + N, srcC, rowptr, P0, a_bias, P3, N);
    k_gru_wx3<<<GT_N2, blk, 0, stream>>>(P3, a_gwx, a_gbx, P0, P2, P5, N);
    k_gru_whf<<<GT_N2, blk, 0, stream>>>(P1, a_gwh, a_gbh, P0, P2, P5, P4, N);

    // ---- atom layer 1: x=P4 -> x=P1. T: Tr=P0, Tz=P2, Tn=P5 ----
    k_mm64t<0,2><<<GT_N, blk, 0, stream>>>(P4, a_linw + 4096, 64, nullptr, P0,
                                           a_asrc + 64, a_adst + 64, scal, scal + N, N);
    k_atom_agg<<<gN4, blk, 0, stream>>>(scal, scal + N, srcC, rowptr, P0, a_bias + 64, P3, N);
    k_gru_wx3<<<GT_N2, blk, 0, stream>>>(P3, a_gwx + 12288, a_gbx + 192, P0, P2, P5, N);
    k_gru_whf<<<GT_N2, blk, 0, stream>>>(P4, a_gwh + 12288, a_gbh + 192, P0, P2, P5, P1, N);

    // ---- readout: x=P1 ----
    k_mm64t<0,1><<<GT_N, blk, 0, stream>>>(P1, m_linw, 64, nullptr, P0,
                                           m_asrcv, nullptr, scal, nullptr, N); // xs + a_src
    k_out0<<<gB4, blk, 0, stream>>>(P1, rpB, outB0, B);
    float* cur = outB0;
    float* nxt = outB1;
    for (int t = 0; t < 3; ++t){
        k_mol_attn<<<gB4, blk, 0, stream>>>(cur, m_linw, m_adstv, scal, P0, rpB, m_bias, hB, B);
        k_gru_wx3<<<GT_B, blk, 0, stream>>>(hB, m_gwx, m_gbx, RB, ZB, XNB, B);
        k_gru_whf<<<GT_B, blk, 0, stream>>>(cur, m_gwh, m_gbh, RB, ZB, XNB, nxt, B);
        float* tmp = cur; cur = nxt; nxt = tmp;
    }

    // ---- head ----
    k_mm64t<0,0><<<GT_B, blk, 0, stream>>>(cur, lin2_w, 64, lin2_b, embB,
                                           nullptr, nullptr, nullptr, nullptr, B);
    k_head<<<gB4, blk, 0, stream>>>(embB, ln_g, ln_b, h1_w, h1_b, h2_w, h2_b, h3_w, h3_b, out, B, P);
}

// Round 16
// 781.764 us; speedup vs baseline: 1.6804x; 1.6804x over previous
//
#include <hip/hip_runtime.h>
#include <cfloat>

#define THREADS 256

// Force a value to stay in a VGPR (no rematerialization past this point).
#define PIN(x) asm volatile("" : "+v"(x))

__device__ __forceinline__ float lrelu01(float v){ return v > 0.f ? v : 0.01f * v; }
__device__ __forceinline__ float reluf(float v){ return v > 0.f ? v : 0.f; }
__device__ __forceinline__ float sigmf(float v){ return 1.f / (1.f + __expf(-v)); }
__device__ __forceinline__ float tanhfast(float v){
    float t = __expf(-2.f * fabsf(v));
    float r = (1.f - t) / (1.f + t);
    return v < 0.f ? -r : r;
}
__device__ __forceinline__ float eluf(float v){ return v > 0.f ? v : __expf(v) - 1.f; }
__device__ __forceinline__ float wmaxf(float v){
    #pragma unroll
    for (int o = 32; o > 0; o >>= 1) v = fmaxf(v, __shfl_xor(v, o, 64));
    return v;
}
__device__ __forceinline__ float wsumf(float v){
    #pragma unroll
    for (int o = 32; o > 0; o >>= 1) v += __shfl_xor(v, o, 64);
    return v;
}

template<int ACT>
__device__ __forceinline__ float actf(float v){
    if (ACT == 1) return lrelu01(v);
    if (ACT == 2) return reluf(v);
    return v;
}

// Stage up to 64 rows (4096 floats) into LDS via async global->LDS DMA (256 thr).
__device__ __forceinline__ void stage_tile(const float* __restrict__ src, float* lds,
                                           int tid, int validf4){
    #pragma unroll
    for (int j = 0; j < 4; ++j){
        int idx = tid + j * 256;
        if (idx < validf4){
            __builtin_amdgcn_global_load_lds(
                (const __attribute__((address_space(1))) void*)(src + (size_t)idx * 4),
                (__attribute__((address_space(3))) void*)(lds + (size_t)idx * 4),
                16, 0, 0);
        }
    }
}

// ---------------- CSR build ----------------
__global__ void k_hist(const int* __restrict__ dst, int* __restrict__ cnt, int E){
    int e = blockIdx.x * blockDim.x + threadIdx.x;
    if (e < E) atomicAdd(&cnt[dst[e]], 1);
}

__global__ void k_scan1(const int* __restrict__ cnt, int* __restrict__ rowptr,
                        int* __restrict__ bsum, int N){
    const int tid = threadIdx.x;
    int i = blockIdx.x * 1024 + tid;
    int v = (i < N) ? cnt[i] : 0;
    int lane = tid & 63, wv = tid >> 6;
    int s = v;
    #pragma unroll
    for (int o = 1; o < 64; o <<= 1){
        int u = __shfl_up(s, o, 64);
        if (lane >= o) s += u;
    }
    __shared__ int wsum[16];
    if (lane == 63) wsum[wv] = s;
    __syncthreads();
    if (wv == 0 && lane < 16){
        int ws = wsum[lane];
        #pragma unroll
        for (int o = 1; o < 16; o <<= 1){
            int u = __shfl_up(ws, o, 64);
            if (lane >= o) ws += u;
        }
        wsum[lane] = ws;
    }
    __syncthreads();
    int woff = wv ? wsum[wv - 1] : 0;
    int incl = s + woff;
    if (i < N) rowptr[i] = incl - v;
    if (tid == 1023) bsum[blockIdx.x] = incl;
}

__global__ void k_scan2(int* __restrict__ bsum, int* __restrict__ rowptr, int NB, int N){
    const int tid = threadIdx.x;
    int v = (tid < NB) ? bsum[tid] : 0;
    int lane = tid & 63, wv = tid >> 6;
    int s = v;
    #pragma unroll
    for (int o = 1; o < 64; o <<= 1){
        int u = __shfl_up(s, o, 64);
        if (lane >= o) s += u;
    }
    __shared__ int wsum[16];
    if (lane == 63) wsum[wv] = s;
    __syncthreads();
    if (wv == 0 && lane < 16){
        int ws = wsum[lane];
        #pragma unroll
        for (int o = 1; o < 16; o <<= 1){
            int u = __shfl_up(ws, o, 64);
            if (lane >= o) ws += u;
        }
        wsum[lane] = ws;
    }
    __syncthreads();
    int woff = wv ? wsum[wv - 1] : 0;
    int incl = s + woff;
    if (tid < NB) bsum[tid] = incl - v;
    if (tid == 1023) rowptr[N] = incl;
}

__global__ void k_scan3(int* __restrict__ rowptr, const int* __restrict__ bsum, int N){
    int i = blockIdx.x * 1024 + threadIdx.x;
    if (i < N) rowptr[i] += bsum[blockIdx.x];
}

// scatter: CSR-ordered src (srcC) + edge->slot mapping (for CSR-ordered logits)
__global__ void k_scatter(const int* __restrict__ dst, const int* __restrict__ srcv,
                          const int* __restrict__ rowptr, int* __restrict__ cnt2,
                          int* __restrict__ srcC, int* __restrict__ slot, int E){
    int e = blockIdx.x * blockDim.x + threadIdx.x;
    if (e < E){
        int d = dst[e];
        int p = rowptr[d] + atomicAdd(&cnt2[d], 1);
        srcC[p] = srcv[e];
        slot[e] = p;
    }
}

__global__ void k_browptr(const int* __restrict__ batch, int* __restrict__ rp, int N, int B){
    int n = blockIdx.x * blockDim.x + threadIdx.x;
    if (n >= N) return;
    int b = batch[n];
    int bp = (n == 0) ? -1 : batch[n - 1];
    for (int g = bp + 1; g <= b; ++g) rp[g] = n;
    if (n == N - 1){ for (int g = b + 1; g <= B; ++g) rp[g] = N; }
}

// ---------- LDS-staged 64-col GEMM (single output) ----------
template<int ACT, int NDOT>
__global__ __launch_bounds__(THREADS, 2)
void k_mm64t(const float* __restrict__ in, const float* __restrict__ W, int ldw,
             const float* __restrict__ bias, float* __restrict__ out,
             const float* __restrict__ v0, const float* __restrict__ v1,
             float* __restrict__ o0, float* __restrict__ o1, int rows){
    __shared__ float tile[2][4096];
    const int tid  = threadIdx.x;
    const int lane = tid & 63;
    const int wv   = tid >> 6;
    float w[64];
    #pragma unroll
    for (int k = 0; k < 64; k += 4){
        float4 t4 = *(const float4*)(W + (size_t)lane * ldw + k);
        w[k] = t4.x; w[k+1] = t4.y; w[k+2] = t4.z; w[k+3] = t4.w;
    }
    #pragma unroll
    for (int k = 0; k < 64; ++k) PIN(w[k]);
    const float bb  = bias ? bias[lane] : 0.f;
    const float vl0 = (NDOT > 0) ? v0[lane] : 0.f;
    const float vl1 = (NDOT > 1) ? v1[lane] : 0.f;
    const int ntiles = (rows + 63) >> 6;
    const int totf4  = rows * 16;
    int t = blockIdx.x;
    if (t >= ntiles) return;
    stage_tile(in + (size_t)t * 4096, tile[0], tid, min(1024, totf4 - t * 1024));
    __syncthreads();
    int b = 0;
    while (t < ntiles){
        int tn = t + gridDim.x;
        if (tn < ntiles)
            stage_tile(in + (size_t)tn * 4096, tile[b ^ 1], tid, min(1024, totf4 - tn * 1024));
        #pragma unroll 4
        for (int r = 0; r < 16; ++r){
            int row = wv * 16 + r;
            int g = t * 64 + row;
            const float4* rp = (const float4*)&tile[b][row * 64];
            float a0 = bb, a1 = 0.f, a2 = 0.f, a3 = 0.f;
            #pragma unroll
            for (int kk = 0; kk < 16; ++kk){
                float4 q = rp[kk];
                a0 = fmaf(q.x, w[kk*4],   a0);
                a1 = fmaf(q.y, w[kk*4+1], a1);
                a2 = fmaf(q.z, w[kk*4+2], a2);
                a3 = fmaf(q.w, w[kk*4+3], a3);
            }
            float v = actf<ACT>((a0 + a1) + (a2 + a3));
            if (g < rows){
                out[(size_t)g * 64 + lane] = v;
                if (NDOT > 0){
                    float s0 = wsumf(v * vl0);
                    float s1 = (NDOT > 1) ? wsumf(v * vl1) : 0.f;
                    if (lane == 0){ o0[g] = s0; if (NDOT > 1) o1[g] = s1; }
                }
            }
        }
        __syncthreads();
        b ^= 1; t = tn;
    }
}

// ---------- Dual GEMM: 128 weights/lane, each row-read serves BOTH outputs ----------
__global__ __launch_bounds__(THREADS, 2)
void k_mm64_x2(const float* __restrict__ in,
               const float* __restrict__ W0, int ldw0,
               const float* __restrict__ W1, int ldw1,
               float* __restrict__ out0, float* __restrict__ out1, int rows){
    __shared__ float tile[2][4096];
    const int tid  = threadIdx.x;
    const int lane = tid & 63;
    const int wv   = tid >> 6;
    float w0[64], w1[64];
    #pragma unroll
    for (int k = 0; k < 64; k += 4){
        float4 a = *(const float4*)(W0 + (size_t)lane * ldw0 + k);
        w0[k] = a.x; w0[k+1] = a.y; w0[k+2] = a.z; w0[k+3] = a.w;
        float4 b4 = *(const float4*)(W1 + (size_t)lane * ldw1 + k);
        w1[k] = b4.x; w1[k+1] = b4.y; w1[k+2] = b4.z; w1[k+3] = b4.w;
    }
    #pragma unroll
    for (int k = 0; k < 64; ++k){ PIN(w0[k]); PIN(w1[k]); }
    const int ntiles = (rows + 63) >> 6;
    const int totf4  = rows * 16;
    int t = blockIdx.x;
    if (t >= ntiles) return;
    stage_tile(in + (size_t)t * 4096, tile[0], tid, min(1024, totf4 - t * 1024));
    __syncthreads();
    int b = 0;
    while (t < ntiles){
        int tn = t + gridDim.x;
        if (tn < ntiles)
            stage_tile(in + (size_t)tn * 4096, tile[b ^ 1], tid, min(1024, totf4 - tn * 1024));
        #pragma unroll 2
        for (int r = 0; r < 16; ++r){
            int row = wv * 16 + r;
            int g = t * 64 + row;
            const float4* rp = (const float4*)&tile[b][row * 64];
            float a0 = 0.f, a1 = 0.f, c0 = 0.f, c1 = 0.f;
            #pragma unroll
            for (int kk = 0; kk < 16; ++kk){
                float4 q = rp[kk];
                a0 = fmaf(q.x, w0[kk*4],   a0);
                a1 = fmaf(q.y, w0[kk*4+1], a1);
                a0 = fmaf(q.z, w0[kk*4+2], a0);
                a1 = fmaf(q.w, w0[kk*4+3], a1);
                c0 = fmaf(q.x, w1[kk*4],   c0);
                c1 = fmaf(q.y, w1[kk*4+1], c1);
                c0 = fmaf(q.z, w1[kk*4+2], c0);
                c1 = fmaf(q.w, w1[kk*4+3], c1);
            }
            if (g < rows){
                out0[(size_t)g * 64 + lane] = a0 + a1;
                out1[(size_t)g * 64 + lane] = c0 + c1;
            }
        }
        __syncthreads();
        b ^= 1; t = tn;
    }
}

// ---------- GRU stage A: all 3 Wx gates per wave (192 w/lane, one read per row) ----------
// NOTE: single-row form. 2-row interleave (R15) spilled (280 live regs) and was 2.6x slower.
__global__ __launch_bounds__(THREADS, 2)
void k_gru_wx3(const float* __restrict__ xin, const float* __restrict__ wx,
               const float* __restrict__ bx,
               float* __restrict__ Tr, float* __restrict__ Tz, float* __restrict__ Tn,
               int rows){
    __shared__ float tile[2][4096];
    const int tid  = threadIdx.x;
    const int lane = tid & 63;
    const int wv   = tid >> 6;
    float wr[64], wz[64], wn[64];
    #pragma unroll
    for (int k = 0; k < 64; k += 4){
        float4 a = *(const float4*)(wx + (size_t)lane * 64 + k);
        wr[k] = a.x; wr[k+1] = a.y; wr[k+2] = a.z; wr[k+3] = a.w;
        float4 b4 = *(const float4*)(wx + (size_t)(64 + lane) * 64 + k);
        wz[k] = b4.x; wz[k+1] = b4.y; wz[k+2] = b4.z; wz[k+3] = b4.w;
        float4 c4 = *(const float4*)(wx + (size_t)(128 + lane) * 64 + k);
        wn[k] = c4.x; wn[k+1] = c4.y; wn[k+2] = c4.z; wn[k+3] = c4.w;
    }
    #pragma unroll
    for (int k = 0; k < 64; ++k){ PIN(wr[k]); PIN(wz[k]); PIN(wn[k]); }
    const float br = bx[lane], bz = bx[64 + lane], bn = bx[128 + lane];
    const int ntiles = (rows + 63) >> 6;
    const int totf4  = rows * 16;
    int t = blockIdx.x;
    if (t >= ntiles) return;
    stage_tile(xin + (size_t)t * 4096, tile[0], tid, min(1024, totf4 - t * 1024));
    __syncthreads();
    int b = 0;
    while (t < ntiles){
        int tn = t + gridDim.x;
        if (tn < ntiles)
            stage_tile(xin + (size_t)tn * 4096, tile[b ^ 1], tid, min(1024, totf4 - tn * 1024));
        #pragma unroll 2
        for (int r = 0; r < 16; ++r){
            int row = wv * 16 + r;
            int g = t * 64 + row;
            const float4* rp = (const float4*)&tile[b][row * 64];
            float r0 = br, r1 = 0.f, z0 = bz, z1 = 0.f, n0 = bn, n1 = 0.f;
            #pragma unroll
            for (int kk = 0; kk < 16; ++kk){
                float4 q = rp[kk];
                r0 = fmaf(q.x, wr[kk*4],   r0);
                r1 = fmaf(q.y, wr[kk*4+1], r1);
                r0 = fmaf(q.z, wr[kk*4+2], r0);
                r1 = fmaf(q.w, wr[kk*4+3], r1);
                z0 = fmaf(q.x, wz[kk*4],   z0);
                z1 = fmaf(q.y, wz[kk*4+1], z1);
                z0 = fmaf(q.z, wz[kk*4+2], z0);
                z1 = fmaf(q.w, wz[kk*4+3], z1);
                n0 = fmaf(q.x, wn[kk*4],   n0);
                n1 = fmaf(q.y, wn[kk*4+1], n1);
                n0 = fmaf(q.z, wn[kk*4+2], n0);
                n1 = fmaf(q.w, wn[kk*4+3], n1);
            }
            if (g < rows){
                size_t idx = (size_t)g * 64 + lane;
                Tr[idx] = r0 + r1;
                Tz[idx] = z0 + z1;
                Tn[idx] = n0 + n1;
            }
        }
        __syncthreads();
        b ^= 1; t = tn;
    }
}

// ---------- GRU stage B: all 3 Wh gates per wave + in-register combine ----------
// T loads hoisted ABOVE the FMA chain so global latency hides under 192 FMAs.
__global__ __launch_bounds__(THREADS, 2)
void k_gru_whf(const float* __restrict__ xp, const float* __restrict__ wh,
               const float* __restrict__ bh,
               const float* __restrict__ Tr, const float* __restrict__ Tz,
               const float* __restrict__ Tn, float* __restrict__ out, int rows){
    __shared__ float tile[2][4096];
    const int tid  = threadIdx.x;
    const int lane = tid & 63;
    const int wv   = tid >> 6;
    float wr[64], wz[64], wn[64];
    #pragma unroll
    for (int k = 0; k < 64; k += 4){
        float4 a = *(const float4*)(wh + (size_t)lane * 64 + k);
        wr[k] = a.x; wr[k+1] = a.y; wr[k+2] = a.z; wr[k+3] = a.w;
        float4 b4 = *(const float4*)(wh + (size_t)(64 + lane) * 64 + k);
        wz[k] = b4.x; wz[k+1] = b4.y; wz[k+2] = b4.z; wz[k+3] = b4.w;
        float4 c4 = *(const float4*)(wh + (size_t)(128 + lane) * 64 + k);
        wn[k] = c4.x; wn[k+1] = c4.y; wn[k+2] = c4.z; wn[k+3] = c4.w;
    }
    #pragma unroll
    for (int k = 0; k < 64; ++k){ PIN(wr[k]); PIN(wz[k]); PIN(wn[k]); }
    const float br = bh[lane], bz = bh[64 + lane], bn = bh[128 + lane];
    const int ntiles = (rows + 63) >> 6;
    const int totf4  = rows * 16;
    int t = blockIdx.x;
    if (t >= ntiles) return;
    stage_tile(xp + (size_t)t * 4096, tile[0], tid, min(1024, totf4 - t * 1024));
    __syncthreads();
    int b = 0;
    while (t < ntiles){
        int tn = t + gridDim.x;
        if (tn < ntiles)
            stage_tile(xp + (size_t)tn * 4096, tile[b ^ 1], tid, min(1024, totf4 - tn * 1024));
        #pragma unroll 2
        for (int r = 0; r < 16; ++r){
            int row = wv * 16 + r;
            int g = t * 64 + row;
            bool ok = g < rows;
            size_t idx = (size_t)g * 64 + lane;
            float trv = 0.f, tzv = 0.f, tnv = 0.f;
            if (ok){ trv = Tr[idx]; tzv = Tz[idx]; tnv = Tn[idx]; }
            float xpv = tile[b][row * 64 + lane];
            const float4* rp = (const float4*)&tile[b][row * 64];
            float r0 = br, r1 = 0.f, z0 = bz, z1 = 0.f, n0 = bn, n1 = 0.f;
            #pragma unroll
            for (int kk = 0; kk < 16; ++kk){
                float4 q = rp[kk];
                r0 = fmaf(q.x, wr[kk*4],   r0);
                r1 = fmaf(q.y, wr[kk*4+1], r1);
                r0 = fmaf(q.z, wr[kk*4+2], r0);
                r1 = fmaf(q.w, wr[kk*4+3], r1);
                z0 = fmaf(q.x, wz[kk*4],   z0);
                z1 = fmaf(q.y, wz[kk*4+1], z1);
                z0 = fmaf(q.z, wz[kk*4+2], z0);
                z1 = fmaf(q.w, wz[kk*4+3], z1);
                n0 = fmaf(q.x, wn[kk*4],   n0);
                n1 = fmaf(q.y, wn[kk*4+1], n1);
                n0 = fmaf(q.z, wn[kk*4+2], n0);
                n1 = fmaf(q.w, wn[kk*4+3], n1);
            }
            if (ok){
                float r_ = sigmf(trv + (r0 + r1));
                float z_ = sigmf(tzv + (z0 + z1));
                float nn = tanhfast(fmaf(r_, n0 + n1, tnv));
                out[idx] = reluf((1.f - z_) * nn + z_ * xpv);
            }
        }
        __syncthreads();
        b ^= 1; t = tn;
    }
}

// GATEConv per-edge logit -> CSR-ordered logitC[slot[e]] (thread-per-edge; at its
// gather-BW floor ~45-50us. Wave-per-edge variant was 3x SLOWER — R14 post-mortem.)
__global__ __launch_bounds__(THREADS, 3)
void k_gate_logit(const float* __restrict__ np1, const float* __restrict__ ea,
                  const float* __restrict__ w1,  // gate_lin1_w [64][80]
                  const float* __restrict__ attl, const float* __restrict__ nat,
                  const int* __restrict__ src, const int* __restrict__ dstv,
                  const int* __restrict__ slot, float* __restrict__ logitC, int E){
    __shared__ float wlds[16 * 64];
    __shared__ float al[64];
    for (int i = threadIdx.x; i < 1024; i += blockDim.x){
        int j = i >> 6, k = i & 63;
        wlds[i] = w1[k * 80 + 64 + j];
    }
    if (threadIdx.x < 64) al[threadIdx.x] = attl[threadIdx.x];
    __syncthreads();
    int e = blockIdx.x * blockDim.x + threadIdx.x;
    if (e >= E) return;
    int s = src[e], d = dstv[e];
    float acc[64];
    const float* nr = np1 + (size_t)s * 64;
    #pragma unroll
    for (int k = 0; k < 64; k += 4){
        float4 t = *(const float4*)(nr + k);
        acc[k] = t.x; acc[k+1] = t.y; acc[k+2] = t.z; acc[k+3] = t.w;
    }
    const float* er = ea + (size_t)e * 16;
    #pragma unroll
    for (int j = 0; j < 16; ++j){
        float v = er[j];
        #pragma unroll
        for (int k = 0; k < 64; k += 4){
            float4 t = *(const float4*)&wlds[j * 64 + k];
            acc[k]   = fmaf(v, t.x, acc[k]);
            acc[k+1] = fmaf(v, t.y, acc[k+1]);
            acc[k+2] = fmaf(v, t.z, acc[k+2]);
            acc[k+3] = fmaf(v, t.w, acc[k+3]);
        }
    }
    float l = 0.f;
    #pragma unroll
    for (int k = 0; k < 64; ++k) l = fmaf(lrelu01(acc[k]), al[k], l);
    logitC[slot[e]] = lrelu01(l + nat[d]);
}

// GATE aggregate: linear CSR reads, 4-way unrolled row gathers
__global__ __launch_bounds__(THREADS, 8)
void k_gate_agg(const float* __restrict__ logitC, const int* __restrict__ srcC,
                const int* __restrict__ rowptr,
                const float* __restrict__ xg, const float* __restrict__ bias,
                float* __restrict__ xin, int N){
    const int lane = threadIdx.x & 63;
    const int d = blockIdx.x * (blockDim.x >> 6) + (threadIdx.x >> 6);
    if (d >= N) return;
    int r0 = rowptr[d], r1 = rowptr[d + 1];
    float m = -3.4e38f;
    for (int j = r0 + lane; j < r1; j += 64) m = fmaxf(m, logitC[j]);
    m = wmaxf(m);
    float s0 = 0.f, s1 = 0.f, s2 = 0.f, s3 = 0.f;
    float h0 = 0.f, h1 = 0.f, h2 = 0.f, h3 = 0.f;
    int j = r0;
    for (; j + 3 < r1; j += 4){
        float l0 = logitC[j], l1 = logitC[j+1], l2 = logitC[j+2], l3 = logitC[j+3];
        int n0 = srcC[j], n1 = srcC[j+1], n2 = srcC[j+2], n3 = srcC[j+3];
        float w0 = __expf(l0 - m), w1 = __expf(l1 - m);
        float w2 = __expf(l2 - m), w3 = __expf(l3 - m);
        s0 += w0; s1 += w1; s2 += w2; s3 += w3;
        h0 = fmaf(w0, xg[(size_t)n0 * 64 + lane], h0);
        h1 = fmaf(w1, xg[(size_t)n1 * 64 + lane], h1);
        h2 = fmaf(w2, xg[(size_t)n2 * 64 + lane], h2);
        h3 = fmaf(w3, xg[(size_t)n3 * 64 + lane], h3);
    }
    for (; j < r1; ++j){
        float w0 = __expf(logitC[j] - m);
        s0 += w0;
        h0 = fmaf(w0, xg[(size_t)srcC[j] * 64 + lane], h0);
    }
    float s = (s0 + s1) + (s2 + s3);
    float hk = (h0 + h1) + (h2 + h3);
    float h = hk / (s + 1e-16f) + bias[lane];
    xin[(size_t)d * 64 + lane] = eluf(h);
}

// GAT aggregate: logits inline from asrc[srcC[j]]+adst[d], 4-way unrolled
__global__ __launch_bounds__(THREADS, 8)
void k_atom_agg(const float* __restrict__ asrc, const float* __restrict__ adst,
                const int* __restrict__ srcC, const int* __restrict__ rowptr,
                const float* __restrict__ xl,
                const float* __restrict__ bias, float* __restrict__ xin, int N){
    const int lane = threadIdx.x & 63;
    const int d = blockIdx.x * (blockDim.x >> 6) + (threadIdx.x >> 6);
    if (d >= N) return;
    int r0 = rowptr[d], r1 = rowptr[d + 1];
    const float ad = adst[d];
    float m = -3.4e38f;
    for (int j = r0 + lane; j < r1; j += 64)
        m = fmaxf(m, lrelu01(asrc[srcC[j]] + ad));
    m = wmaxf(m);
    float s0 = 0.f, s1 = 0.f, s2 = 0.f, s3 = 0.f;
    float h0 = 0.f, h1 = 0.f, h2 = 0.f, h3 = 0.f;
    int j = r0;
    for (; j + 3 < r1; j += 4){
        int n0 = srcC[j], n1 = srcC[j+1], n2 = srcC[j+2], n3 = srcC[j+3];
        float w0 = __expf(lrelu01(asrc[n0] + ad) - m);
        float w1 = __expf(lrelu01(asrc[n1] + ad) - m);
        float w2 = __expf(lrelu01(asrc[n2] + ad) - m);
        float w3 = __expf(lrelu01(asrc[n3] + ad) - m);
        s0 += w0; s1 += w1; s2 += w2; s3 += w3;
        h0 = fmaf(w0, xl[(size_t)n0 * 64 + lane], h0);
        h1 = fmaf(w1, xl[(size_t)n1 * 64 + lane], h1);
        h2 = fmaf(w2, xl[(size_t)n2 * 64 + lane], h2);
        h3 = fmaf(w3, xl[(size_t)n3 * 64 + lane], h3);
    }
    for (; j < r1; ++j){
        int n0 = srcC[j];
        float w0 = __expf(lrelu01(asrc[n0] + ad) - m);
        s0 += w0;
        h0 = fmaf(w0, xl[(size_t)n0 * 64 + lane], h0);
    }
    float s = (s0 + s1) + (s2 + s3);
    float hk = (h0 + h1) + (h2 + h3);
    float h = hk / (s + 1e-16f) + bias[lane];
    xin[(size_t)d * 64 + lane] = eluf(h);
}

// out0[b] = relu(sum over nodes of graph b)
__global__ __launch_bounds__(THREADS, 4)
void k_out0(const float* __restrict__ x, const int* __restrict__ rpB,
            float* __restrict__ outB, int B){
    const int lane = threadIdx.x & 63;
    const int b = blockIdx.x * (blockDim.x >> 6) + (threadIdx.x >> 6);
    if (b >= B) return;
    int r0 = rpB[b], r1 = rpB[b + 1];
    float a = 0.f;
    for (int n = r0; n < r1; ++n) a += x[(size_t)n * 64 + lane];
    outB[(size_t)b * 64 + lane] = reluf(a);
}

// readout attention step
__global__ __launch_bounds__(THREADS, 2)
void k_mol_attn(const float* __restrict__ outB, const float* __restrict__ W,
                const float* __restrict__ attdst, const float* __restrict__ a_src,
                const float* __restrict__ xs, const int* __restrict__ rpB,
                const float* __restrict__ bias, float* __restrict__ hB, int B){
    const int lane = threadIdx.x & 63;
    const int b = blockIdx.x * (blockDim.x >> 6) + (threadIdx.x >> 6);
    if (b >= B) return;
    float w[64];
    #pragma unroll
    for (int k = 0; k < 64; k += 4){
        float4 t = *(const float4*)(W + (size_t)lane * 64 + k);
        w[k] = t.x; w[k+1] = t.y; w[k+2] = t.z; w[k+3] = t.w;
    }
    const float* orow = outB + (size_t)b * 64;
    float acc = 0.f;
    #pragma unroll
    for (int k = 0; k < 64; ++k) acc = fmaf(orow[k], w[k], acc);
    float g = wsumf(acc * attdst[lane]);
    int r0 = rpB[b], r1 = rpB[b + 1];
    float m = -3.4e38f;
    for (int n = r0 + lane; n < r1; n += 64) m = fmaxf(m, lrelu01(a_src[n] + g));
    m = wmaxf(m);
    float s = 0.f, hk = 0.f;
    for (int n = r0; n < r1; ++n){
        float l = lrelu01(a_src[n] + g);
        float ww = __expf(l - m);
        s += ww;
        hk = fmaf(ww, xs[(size_t)n * 64 + lane], hk);
    }
    hB[(size_t)b * 64 + lane] = eluf(hk / (s + 1e-16f) + bias[lane]);
}

// regression head
__global__ void k_head(const float* __restrict__ emb, const float* __restrict__ lng,
                       const float* __restrict__ lnb,
                       const float* __restrict__ w1, const float* __restrict__ b1,
                       const float* __restrict__ w2, const float* __restrict__ b2,
                       const float* __restrict__ w3, const float* __restrict__ b3,
                       float* __restrict__ out, int B, int P){
    __shared__ float w1t[4096], w2t[4096];
    __shared__ float buf0[4][64], buf1[4][64];
    for (int i = threadIdx.x; i < 4096; i += blockDim.x){
        int h = i >> 6, k = i & 63;
        w1t[k * 64 + h] = w1[i];
        w2t[k * 64 + h] = w2[i];
    }
    __syncthreads();
    const int lane = threadIdx.x & 63;
    const int wv = threadIdx.x >> 6;
    int b = blockIdx.x * (blockDim.x >> 6) + wv;
    bool act = b < B;
    float v = act ? emb[(size_t)b * 64 + lane] : 0.f;
    float mean = wsumf(v) * 0.015625f;
    float dv = v - mean;
    float var = wsumf(dv * dv) * 0.015625f;
    float y = dv * rsqrtf(var + 1e-5f) * lng[lane] + lnb[lane];
    buf0[wv][lane] = y;
    __syncthreads();
    float a1 = b1[lane];
    #pragma unroll
    for (int k = 0; k < 64; ++k) a1 = fmaf(buf0[wv][k], w1t[k * 64 + lane], a1);
    float y1 = reluf(a1);
    buf1[wv][lane] = y1;
    __syncthreads();
    float a2 = b2[lane];
    #pragma unroll
    for (int k = 0; k < 64; ++k) a2 = fmaf(buf1[wv][k], w2t[k * 64 + lane], a2);
    float y2 = reluf(a2);
    for (int p = 0; p < P; ++p){
        float s = wsumf(y2 * w3[p * 64 + lane]);
        if (lane == 0 && act) out[(size_t)b * P + p] = s + b3[p];
    }
}

extern "C" void kernel_launch(void* const* d_in, const int* in_sizes, int n_in,
                              void* d_out, int out_size, void* d_ws, size_t ws_size,
                              hipStream_t stream){
    const float* x       = (const float*)d_in[0];
    const float* eattr   = (const float*)d_in[1];
    const float* lin1_w  = (const float*)d_in[2];
    const float* lin1_b  = (const float*)d_in[3];
    const float* g_l1w   = (const float*)d_in[4];
    const float* g_l2w   = (const float*)d_in[5];
    const float* g_attl  = (const float*)d_in[6];
    const float* g_attr  = (const float*)d_in[7];
    const float* g_bias  = (const float*)d_in[8];
    const float* gru0_wx = (const float*)d_in[9];
    const float* gru0_wh = (const float*)d_in[10];
    const float* gru0_bx = (const float*)d_in[11];
    const float* gru0_bh = (const float*)d_in[12];
    const float* a_linw  = (const float*)d_in[13];
    const float* a_asrc  = (const float*)d_in[14];
    const float* a_adst  = (const float*)d_in[15];
    const float* a_bias  = (const float*)d_in[16];
    const float* a_gwx   = (const float*)d_in[17];
    const float* a_gwh   = (const float*)d_in[18];
    const float* a_gbx   = (const float*)d_in[19];
    const float* a_gbh   = (const float*)d_in[20];
    const float* m_linw  = (const float*)d_in[21];
    const float* m_asrcv = (const float*)d_in[22];
    const float* m_adstv = (const float*)d_in[23];
    const float* m_bias  = (const float*)d_in[24];
    const float* m_gwx   = (const float*)d_in[25];
    const float* m_gwh   = (const float*)d_in[26];
    const float* m_gbx   = (const float*)d_in[27];
    const float* m_gbh   = (const float*)d_in[28];
    const float* lin2_w  = (const float*)d_in[29];
    const float* lin2_b  = (const float*)d_in[30];
    const float* ln_g    = (const float*)d_in[31];
    const float* ln_b    = (const float*)d_in[32];
    const float* h1_w    = (const float*)d_in[33];
    const float* h1_b    = (const float*)d_in[34];
    const float* h2_w    = (const float*)d_in[35];
    const float* h2_b    = (const float*)d_in[36];
    const float* h3_w    = (const float*)d_in[37];
    const float* h3_b    = (const float*)d_in[38];
    const int*   ei      = (const int*)d_in[39];
    const int*   batch   = (const int*)d_in[40];
    float* out = (float*)d_out;

    const int N = in_sizes[0] / 64;
    const int E = in_sizes[1] / 16;
    const int P = in_sizes[38];
    const int B = out_size / (P > 0 ? P : 1);
    const int* srcv = ei;
    const int* dstv = ei + E;

    // ---- workspace layout ----
    float* Wb = (float*)d_ws;
    size_t nb = (size_t)N * 64;
    size_t bb = (size_t)B * 64;
    float* P0 = Wb;
    float* P1 = P0 + nb;
    float* P2 = P1 + nb;
    float* P3 = P2 + nb;
    float* P4 = P3 + nb;
    float* P5 = P4 + nb;
    float* logitC = P5 + nb;
    float* scal  = logitC + E;
    float* outB0 = scal + 2 * (size_t)N;
    float* outB1 = outB0 + bb;
    float* hB    = outB1 + bb;
    float* RB    = hB + bb;
    float* ZB    = RB + bb;
    float* XNB   = ZB + bb;
    int* srcC   = (int*)(XNB + bb);
    int* slot   = srcC + E;
    int* rowptr = slot + E;
    int* cnt    = rowptr + (N + 1);
    int* cnt2   = cnt + N;
    int* rpB    = cnt2 + N;
    int* bsum   = rpB + (B + 1);
    const int NB = (N + 1023) >> 10;
    size_t need = (size_t)((char*)(bsum + NB) - (char*)d_ws);
    if (need > ws_size) return;
    float* embB = XNB;

    dim3 blk(THREADS);
    int gE    = (E + THREADS - 1) / THREADS;
    int gN4   = (N + 3) / 4;
    int gB4   = (B + 3) / 4;
    int gN256 = (N + THREADS - 1) / THREADS;
    int ntN   = (N + 63) >> 6;
    int ntB   = (B + 63) >> 6;
    int GT_N  = ntN < 768 ? ntN : 768;   // 3 blocks/CU tile kernels
    int GT_N2 = ntN < 512 ? ntN : 512;   // 2 blocks/CU (high-VGPR fused kernels)
    int GT_B  = ntB;

    // ---- CSR build ----
    hipMemsetAsync(cnt, 0, sizeof(int) * 2 * (size_t)N, stream);
    k_hist<<<gE, blk, 0, stream>>>(dstv, cnt, E);
    k_scan1<<<NB, 1024, 0, stream>>>(cnt, rowptr, bsum, N);
    k_scan2<<<1, 1024, 0, stream>>>(bsum, rowptr, NB, N);
    k_scan3<<<NB, 1024, 0, stream>>>(rowptr, bsum, N);
    k_scatter<<<gE, blk, 0, stream>>>(dstv, srcv, rowptr, cnt2, srcC, slot, E);
    k_browptr<<<gN256, blk, 0, stream>>>(batch, rpB, N, B);

    // ---- phase 0: x1 = lrelu(x@lin1+b) -> P0, fused nat -> scal ----
    k_mm64t<1,1><<<GT_N, blk, 0, stream>>>(x, lin1_w, 64, lin1_b, P0,
                                           g_attr, nullptr, scal, nullptr, N);

    // ---- GATEConv ----
    k_mm64_x2<<<GT_N2, blk, 0, stream>>>(P0, g_l1w, 80, g_l2w, 64, P1, P2, N); // np1, xg
    k_gate_logit<<<gE, blk, 0, stream>>>(P1, eattr, g_l1w, g_attl, scal, srcv, dstv,
                                         slot, logitC, E);
    k_gate_agg<<<gN4, blk, 0, stream>>>(logitC, srcC, rowptr, P2, g_bias, P3, N);
    // GRU0: xin=P3, xp=P0 -> x=P1. T: Tr=P2, Tz=P5, Tn=P4
    k_gru_wx3<<<GT_N2, blk, 0, stream>>>(P3, gru0_wx, gru0_bx, P2, P5, P4, N);
    k_gru_whf<<<GT_N2, blk, 0, stream>>>(P0, gru0_wh, gru0_bh, P2, P5, P4, P1, N);

    // ---- atom layer 0: x=P1 -> x=P4. T: Tr=P0, Tz=P2, Tn=P5 ----
    k_mm64t<0,2><<<GT_N, blk, 0, stream>>>(P1, a_linw, 64, nullptr, P0,
                                           a_asrc, a_adst, scal, scal + N, N);
    k_atom_agg<<<gN4, blk, 0, stream>>>(scal, scal + N, srcC, rowptr, P0, a_bias, P3, N);
    k_gru_wx3<<<GT_N2, blk, 0, stream>>>(P3, a_gwx, a_gbx, P0, P2, P5, N);
    k_gru_whf<<<GT_N2, blk, 0, stream>>>(P1, a_gwh, a_gbh, P0, P2, P5, P4, N);

    // ---- atom layer 1: x=P4 -> x=P1. T: Tr=P0, Tz=P2, Tn=P5 ----
    k_mm64t<0,2><<<GT_N, blk, 0, stream>>>(P4, a_linw + 4096, 64, nullptr, P0,
                                           a_asrc + 64, a_adst + 64, scal, scal + N, N);
    k_atom_agg<<<gN4, blk, 0, stream>>>(scal, scal + N, srcC, rowptr, P0, a_bias + 64, P3, N);
    k_gru_wx3<<<GT_N2, blk, 0, stream>>>(P3, a_gwx + 12288, a_gbx + 192, P0, P2, P5, N);
    k_gru_whf<<<GT_N2, blk, 0, stream>>>(P4, a_gwh + 12288, a_gbh + 192, P0, P2, P5, P1, N);

    // ---- readout: x=P1 ----
    k_mm64t<0,1><<<GT_N, blk, 0, stream>>>(P1, m_linw, 64, nullptr, P0,
                                           m_asrcv, nullptr, scal, nullptr, N); // xs + a_src
    k_out0<<<gB4, blk, 0, stream>>>(P1, rpB, outB0, B);
    float* cur = outB0;
    float* nxt = outB1;
    for (int t = 0; t < 3; ++t){
        k_mol_attn<<<gB4, blk, 0, stream>>>(cur, m_linw, m_adstv, scal, P0, rpB, m_bias, hB, B);
        k_gru_wx3<<<GT_B, blk, 0, stream>>>(hB, m_gwx, m_gbx, RB, ZB, XNB, B);
        k_gru_whf<<<GT_B, blk, 0, stream>>>(cur, m_gwh, m_gbh, RB, ZB, XNB, nxt, B);
        float* tmp = cur; cur = nxt; nxt = tmp;
    }

    // ---- head ----
    k_mm64t<0,0><<<GT_B, blk, 0, stream>>>(cur, lin2_w, 64, lin2_b, embB,
                                           nullptr, nullptr, nullptr, nullptr, B);
    k_head<<<gB4, blk, 0, stream>>>(embB, ln_g, ln_b, h1_w, h1_b, h2_w, h2_b, h3_w, h3_b, out, B, P);
}

// Round 17
// 777.452 us; speedup vs baseline: 1.6897x; 1.0055x over previous
//
#include <hip/hip_runtime.h>
#include <cfloat>

#define THREADS 256

// Force a value to stay in a VGPR (no rematerialization past this point).
#define PIN(x) asm volatile("" : "+v"(x))

__device__ __forceinline__ float lrelu01(float v){ return v > 0.f ? v : 0.01f * v; }
__device__ __forceinline__ float reluf(float v){ return v > 0.f ? v : 0.f; }
__device__ __forceinline__ float sigmf(float v){ return 1.f / (1.f + __expf(-v)); }
__device__ __forceinline__ float tanhfast(float v){
    float t = __expf(-2.f * fabsf(v));
    float r = (1.f - t) / (1.f + t);
    return v < 0.f ? -r : r;
}
__device__ __forceinline__ float eluf(float v){ return v > 0.f ? v : __expf(v) - 1.f; }
__device__ __forceinline__ float wmaxf(float v){
    #pragma unroll
    for (int o = 32; o > 0; o >>= 1) v = fmaxf(v, __shfl_xor(v, o, 64));
    return v;
}
__device__ __forceinline__ float wsumf(float v){
    #pragma unroll
    for (int o = 32; o > 0; o >>= 1) v += __shfl_xor(v, o, 64);
    return v;
}

template<int ACT>
__device__ __forceinline__ float actf(float v){
    if (ACT == 1) return lrelu01(v);
    if (ACT == 2) return reluf(v);
    return v;
}

// Stage up to 64 rows (4096 floats) into LDS via async global->LDS DMA (256 thr).
__device__ __forceinline__ void stage_tile(const float* __restrict__ src, float* lds,
                                           int tid, int validf4){
    #pragma unroll
    for (int j = 0; j < 4; ++j){
        int idx = tid + j * 256;
        if (idx < validf4){
            __builtin_amdgcn_global_load_lds(
                (const __attribute__((address_space(1))) void*)(src + (size_t)idx * 4),
                (__attribute__((address_space(3))) void*)(lds + (size_t)idx * 4),
                16, 0, 0);
        }
    }
}

// ---------------- CSR build ----------------
__global__ void k_hist(const int* __restrict__ dst, int* __restrict__ cnt, int E){
    int e = blockIdx.x * blockDim.x + threadIdx.x;
    if (e < E) atomicAdd(&cnt[dst[e]], 1);
}

__global__ void k_scan1(const int* __restrict__ cnt, int* __restrict__ rowptr,
                        int* __restrict__ bsum, int N){
    const int tid = threadIdx.x;
    int i = blockIdx.x * 1024 + tid;
    int v = (i < N) ? cnt[i] : 0;
    int lane = tid & 63, wv = tid >> 6;
    int s = v;
    #pragma unroll
    for (int o = 1; o < 64; o <<= 1){
        int u = __shfl_up(s, o, 64);
        if (lane >= o) s += u;
    }
    __shared__ int wsum[16];
    if (lane == 63) wsum[wv] = s;
    __syncthreads();
    if (wv == 0 && lane < 16){
        int ws = wsum[lane];
        #pragma unroll
        for (int o = 1; o < 16; o <<= 1){
            int u = __shfl_up(ws, o, 64);
            if (lane >= o) ws += u;
        }
        wsum[lane] = ws;
    }
    __syncthreads();
    int woff = wv ? wsum[wv - 1] : 0;
    int incl = s + woff;
    if (i < N) rowptr[i] = incl - v;
    if (tid == 1023) bsum[blockIdx.x] = incl;
}

__global__ void k_scan2(int* __restrict__ bsum, int* __restrict__ rowptr, int NB, int N){
    const int tid = threadIdx.x;
    int v = (tid < NB) ? bsum[tid] : 0;
    int lane = tid & 63, wv = tid >> 6;
    int s = v;
    #pragma unroll
    for (int o = 1; o < 64; o <<= 1){
        int u = __shfl_up(s, o, 64);
        if (lane >= o) s += u;
    }
    __shared__ int wsum[16];
    if (lane == 63) wsum[wv] = s;
    __syncthreads();
    if (wv == 0 && lane < 16){
        int ws = wsum[lane];
        #pragma unroll
        for (int o = 1; o < 16; o <<= 1){
            int u = __shfl_up(ws, o, 64);
            if (lane >= o) ws += u;
        }
        wsum[lane] = ws;
    }
    __syncthreads();
    int woff = wv ? wsum[wv - 1] : 0;
    int incl = s + woff;
    if (tid < NB) bsum[tid] = incl - v;
    if (tid == 1023) rowptr[N] = incl;
}

__global__ void k_scan3(int* __restrict__ rowptr, const int* __restrict__ bsum, int N){
    int i = blockIdx.x * 1024 + threadIdx.x;
    if (i < N) rowptr[i] += bsum[blockIdx.x];
}

// scatter: CSR-ordered src (srcC) + edge->slot mapping (for CSR-ordered logits)
__global__ void k_scatter(const int* __restrict__ dst, const int* __restrict__ srcv,
                          const int* __restrict__ rowptr, int* __restrict__ cnt2,
                          int* __restrict__ srcC, int* __restrict__ slot, int E){
    int e = blockIdx.x * blockDim.x + threadIdx.x;
    if (e < E){
        int d = dst[e];
        int p = rowptr[d] + atomicAdd(&cnt2[d], 1);
        srcC[p] = srcv[e];
        slot[e] = p;
    }
}

__global__ void k_browptr(const int* __restrict__ batch, int* __restrict__ rp, int N, int B){
    int n = blockIdx.x * blockDim.x + threadIdx.x;
    if (n >= N) return;
    int b = batch[n];
    int bp = (n == 0) ? -1 : batch[n - 1];
    for (int g = bp + 1; g <= b; ++g) rp[g] = n;
    if (n == N - 1){ for (int g = b + 1; g <= B; ++g) rp[g] = N; }
}

// ---------- LDS-staged 64-col GEMM (single output) ----------
template<int ACT, int NDOT>
__global__ __launch_bounds__(THREADS, 2)
void k_mm64t(const float* __restrict__ in, const float* __restrict__ W, int ldw,
             const float* __restrict__ bias, float* __restrict__ out,
             const float* __restrict__ v0, const float* __restrict__ v1,
             float* __restrict__ o0, float* __restrict__ o1, int rows){
    __shared__ float tile[2][4096];
    const int tid  = threadIdx.x;
    const int lane = tid & 63;
    const int wv   = tid >> 6;
    float w[64];
    #pragma unroll
    for (int k = 0; k < 64; k += 4){
        float4 t4 = *(const float4*)(W + (size_t)lane * ldw + k);
        w[k] = t4.x; w[k+1] = t4.y; w[k+2] = t4.z; w[k+3] = t4.w;
    }
    #pragma unroll
    for (int k = 0; k < 64; ++k) PIN(w[k]);
    const float bb  = bias ? bias[lane] : 0.f;
    const float vl0 = (NDOT > 0) ? v0[lane] : 0.f;
    const float vl1 = (NDOT > 1) ? v1[lane] : 0.f;
    const int ntiles = (rows + 63) >> 6;
    const int totf4  = rows * 16;
    int t = blockIdx.x;
    if (t >= ntiles) return;
    stage_tile(in + (size_t)t * 4096, tile[0], tid, min(1024, totf4 - t * 1024));
    __syncthreads();
    int b = 0;
    while (t < ntiles){
        int tn = t + gridDim.x;
        if (tn < ntiles)
            stage_tile(in + (size_t)tn * 4096, tile[b ^ 1], tid, min(1024, totf4 - tn * 1024));
        #pragma unroll 4
        for (int r = 0; r < 16; ++r){
            int row = wv * 16 + r;
            int g = t * 64 + row;
            const float4* rp = (const float4*)&tile[b][row * 64];
            float a0 = bb, a1 = 0.f, a2 = 0.f, a3 = 0.f;
            #pragma unroll
            for (int kk = 0; kk < 16; ++kk){
                float4 q = rp[kk];
                a0 = fmaf(q.x, w[kk*4],   a0);
                a1 = fmaf(q.y, w[kk*4+1], a1);
                a2 = fmaf(q.z, w[kk*4+2], a2);
                a3 = fmaf(q.w, w[kk*4+3], a3);
            }
            float v = actf<ACT>((a0 + a1) + (a2 + a3));
            if (g < rows){
                out[(size_t)g * 64 + lane] = v;
                if (NDOT > 0){
                    float s0 = wsumf(v * vl0);
                    float s1 = (NDOT > 1) ? wsumf(v * vl1) : 0.f;
                    if (lane == 0){ o0[g] = s0; if (NDOT > 1) o1[g] = s1; }
                }
            }
        }
        __syncthreads();
        b ^= 1; t = tn;
    }
}

// ---------- Dual GEMM: 128 weights/lane, each row-read serves BOTH outputs ----------
__global__ __launch_bounds__(THREADS, 2)
void k_mm64_x2(const float* __restrict__ in,
               const float* __restrict__ W0, int ldw0,
               const float* __restrict__ W1, int ldw1,
               float* __restrict__ out0, float* __restrict__ out1, int rows){
    __shared__ float tile[2][4096];
    const int tid  = threadIdx.x;
    const int lane = tid & 63;
    const int wv   = tid >> 6;
    float w0[64], w1[64];
    #pragma unroll
    for (int k = 0; k < 64; k += 4){
        float4 a = *(const float4*)(W0 + (size_t)lane * ldw0 + k);
        w0[k] = a.x; w0[k+1] = a.y; w0[k+2] = a.z; w0[k+3] = a.w;
        float4 b4 = *(const float4*)(W1 + (size_t)lane * ldw1 + k);
        w1[k] = b4.x; w1[k+1] = b4.y; w1[k+2] = b4.z; w1[k+3] = b4.w;
    }
    #pragma unroll
    for (int k = 0; k < 64; ++k){ PIN(w0[k]); PIN(w1[k]); }
    const int ntiles = (rows + 63) >> 6;
    const int totf4  = rows * 16;
    int t = blockIdx.x;
    if (t >= ntiles) return;
    stage_tile(in + (size_t)t * 4096, tile[0], tid, min(1024, totf4 - t * 1024));
    __syncthreads();
    int b = 0;
    while (t < ntiles){
        int tn = t + gridDim.x;
        if (tn < ntiles)
            stage_tile(in + (size_t)tn * 4096, tile[b ^ 1], tid, min(1024, totf4 - tn * 1024));
        #pragma unroll 2
        for (int r = 0; r < 16; ++r){
            int row = wv * 16 + r;
            int g = t * 64 + row;
            const float4* rp = (const float4*)&tile[b][row * 64];
            float a0 = 0.f, a1 = 0.f, c0 = 0.f, c1 = 0.f;
            #pragma unroll
            for (int kk = 0; kk < 16; ++kk){
                float4 q = rp[kk];
                a0 = fmaf(q.x, w0[kk*4],   a0);
                a1 = fmaf(q.y, w0[kk*4+1], a1);
                a0 = fmaf(q.z, w0[kk*4+2], a0);
                a1 = fmaf(q.w, w0[kk*4+3], a1);
                c0 = fmaf(q.x, w1[kk*4],   c0);
                c1 = fmaf(q.y, w1[kk*4+1], c1);
                c0 = fmaf(q.z, w1[kk*4+2], c0);
                c1 = fmaf(q.w, w1[kk*4+3], c1);
            }
            if (g < rows){
                out0[(size_t)g * 64 + lane] = a0 + a1;
                out1[(size_t)g * 64 + lane] = c0 + c1;
            }
        }
        __syncthreads();
        b ^= 1; t = tn;
    }
}

// ---------- GRU stage A: all 3 Wx gates per wave (192 w/lane, one read per row) ----------
// NOTE: single-row form. 2-row interleave (R15) spilled (280 live regs) and was 2.6x slower.
__global__ __launch_bounds__(THREADS, 2)
void k_gru_wx3(const float* __restrict__ xin, const float* __restrict__ wx,
               const float* __restrict__ bx,
               float* __restrict__ Tr, float* __restrict__ Tz, float* __restrict__ Tn,
               int rows){
    __shared__ float tile[2][4096];
    const int tid  = threadIdx.x;
    const int lane = tid & 63;
    const int wv   = tid >> 6;
    float wr[64], wz[64], wn[64];
    #pragma unroll
    for (int k = 0; k < 64; k += 4){
        float4 a = *(const float4*)(wx + (size_t)lane * 64 + k);
        wr[k] = a.x; wr[k+1] = a.y; wr[k+2] = a.z; wr[k+3] = a.w;
        float4 b4 = *(const float4*)(wx + (size_t)(64 + lane) * 64 + k);
        wz[k] = b4.x; wz[k+1] = b4.y; wz[k+2] = b4.z; wz[k+3] = b4.w;
        float4 c4 = *(const float4*)(wx + (size_t)(128 + lane) * 64 + k);
        wn[k] = c4.x; wn[k+1] = c4.y; wn[k+2] = c4.z; wn[k+3] = c4.w;
    }
    #pragma unroll
    for (int k = 0; k < 64; ++k){ PIN(wr[k]); PIN(wz[k]); PIN(wn[k]); }
    const float br = bx[lane], bz = bx[64 + lane], bn = bx[128 + lane];
    const int ntiles = (rows + 63) >> 6;
    const int totf4  = rows * 16;
    int t = blockIdx.x;
    if (t >= ntiles) return;
    stage_tile(xin + (size_t)t * 4096, tile[0], tid, min(1024, totf4 - t * 1024));
    __syncthreads();
    int b = 0;
    while (t < ntiles){
        int tn = t + gridDim.x;
        if (tn < ntiles)
            stage_tile(xin + (size_t)tn * 4096, tile[b ^ 1], tid, min(1024, totf4 - tn * 1024));
        #pragma unroll 2
        for (int r = 0; r < 16; ++r){
            int row = wv * 16 + r;
            int g = t * 64 + row;
            const float4* rp = (const float4*)&tile[b][row * 64];
            float r0 = br, r1 = 0.f, z0 = bz, z1 = 0.f, n0 = bn, n1 = 0.f;
            #pragma unroll
            for (int kk = 0; kk < 16; ++kk){
                float4 q = rp[kk];
                r0 = fmaf(q.x, wr[kk*4],   r0);
                r1 = fmaf(q.y, wr[kk*4+1], r1);
                r0 = fmaf(q.z, wr[kk*4+2], r0);
                r1 = fmaf(q.w, wr[kk*4+3], r1);
                z0 = fmaf(q.x, wz[kk*4],   z0);
                z1 = fmaf(q.y, wz[kk*4+1], z1);
                z0 = fmaf(q.z, wz[kk*4+2], z0);
                z1 = fmaf(q.w, wz[kk*4+3], z1);
                n0 = fmaf(q.x, wn[kk*4],   n0);
                n1 = fmaf(q.y, wn[kk*4+1], n1);
                n0 = fmaf(q.z, wn[kk*4+2], n0);
                n1 = fmaf(q.w, wn[kk*4+3], n1);
            }
            if (g < rows){
                size_t idx = (size_t)g * 64 + lane;
                Tr[idx] = r0 + r1;
                Tz[idx] = z0 + z1;
                Tn[idx] = n0 + n1;
            }
        }
        __syncthreads();
        b ^= 1; t = tn;
    }
}

// ---------- GRU stage B: all 3 Wh gates per wave + in-register combine ----------
// T loads hoisted ABOVE the FMA chain so global latency hides under 192 FMAs.
__global__ __launch_bounds__(THREADS, 2)
void k_gru_whf(const float* __restrict__ xp, const float* __restrict__ wh,
               const float* __restrict__ bh,
               const float* __restrict__ Tr, const float* __restrict__ Tz,
               const float* __restrict__ Tn, float* __restrict__ out, int rows){
    __shared__ float tile[2][4096];
    const int tid  = threadIdx.x;
    const int lane = tid & 63;
    const int wv   = tid >> 6;
    float wr[64], wz[64], wn[64];
    #pragma unroll
    for (int k = 0; k < 64; k += 4){
        float4 a = *(const float4*)(wh + (size_t)lane * 64 + k);
        wr[k] = a.x; wr[k+1] = a.y; wr[k+2] = a.z; wr[k+3] = a.w;
        float4 b4 = *(const float4*)(wh + (size_t)(64 + lane) * 64 + k);
        wz[k] = b4.x; wz[k+1] = b4.y; wz[k+2] = b4.z; wz[k+3] = b4.w;
        float4 c4 = *(const float4*)(wh + (size_t)(128 + lane) * 64 + k);
        wn[k] = c4.x; wn[k+1] = c4.y; wn[k+2] = c4.z; wn[k+3] = c4.w;
    }
    #pragma unroll
    for (int k = 0; k < 64; ++k){ PIN(wr[k]); PIN(wz[k]); PIN(wn[k]); }
    const float br = bh[lane], bz = bh[64 + lane], bn = bh[128 + lane];
    const int ntiles = (rows + 63) >> 6;
    const int totf4  = rows * 16;
    int t = blockIdx.x;
    if (t >= ntiles) return;
    stage_tile(xp + (size_t)t * 4096, tile[0], tid, min(1024, totf4 - t * 1024));
    __syncthreads();
    int b = 0;
    while (t < ntiles){
        int tn = t + gridDim.x;
        if (tn < ntiles)
            stage_tile(xp + (size_t)tn * 4096, tile[b ^ 1], tid, min(1024, totf4 - tn * 1024));
        #pragma unroll 2
        for (int r = 0; r < 16; ++r){
            int row = wv * 16 + r;
            int g = t * 64 + row;
            bool ok = g < rows;
            size_t idx = (size_t)g * 64 + lane;
            float trv = 0.f, tzv = 0.f, tnv = 0.f;
            if (ok){ trv = Tr[idx]; tzv = Tz[idx]; tnv = Tn[idx]; }
            float xpv = tile[b][row * 64 + lane];
            const float4* rp = (const float4*)&tile[b][row * 64];
            float r0 = br, r1 = 0.f, z0 = bz, z1 = 0.f, n0 = bn, n1 = 0.f;
            #pragma unroll
            for (int kk = 0; kk < 16; ++kk){
                float4 q = rp[kk];
                r0 = fmaf(q.x, wr[kk*4],   r0);
                r1 = fmaf(q.y, wr[kk*4+1], r1);
                r0 = fmaf(q.z, wr[kk*4+2], r0);
                r1 = fmaf(q.w, wr[kk*4+3], r1);
                z0 = fmaf(q.x, wz[kk*4],   z0);
                z1 = fmaf(q.y, wz[kk*4+1], z1);
                z0 = fmaf(q.z, wz[kk*4+2], z0);
                z1 = fmaf(q.w, wz[kk*4+3], z1);
                n0 = fmaf(q.x, wn[kk*4],   n0);
                n1 = fmaf(q.y, wn[kk*4+1], n1);
                n0 = fmaf(q.z, wn[kk*4+2], n0);
                n1 = fmaf(q.w, wn[kk*4+3], n1);
            }
            if (ok){
                float r_ = sigmf(trv + (r0 + r1));
                float z_ = sigmf(tzv + (z0 + z1));
                float nn = tanhfast(fmaf(r_, n0 + n1, tnv));
                out[idx] = reluf((1.f - z_) * nn + z_ * xpv);
            }
        }
        __syncthreads();
        b ^= 1; t = tn;
    }
}

// GATEConv per-edge logit -> CSR-ordered logitC[slot[e]]. Thread-per-edge.
// (256,2) + PIN: at (256,3) the allocator parked acc[64] in scratch (VGPR=60,
// ~14MB spill writes — R16 profile). Same fix pattern as R2->R3 GEMM weights.
__global__ __launch_bounds__(THREADS, 2)
void k_gate_logit(const float* __restrict__ np1, const float* __restrict__ ea,
                  const float* __restrict__ w1,  // gate_lin1_w [64][80]
                  const float* __restrict__ attl, const float* __restrict__ nat,
                  const int* __restrict__ src, const int* __restrict__ dstv,
                  const int* __restrict__ slot, float* __restrict__ logitC, int E){
    __shared__ float wlds[16 * 64];
    __shared__ float al[64];
    for (int i = threadIdx.x; i < 1024; i += blockDim.x){
        int j = i >> 6, k = i & 63;
        wlds[i] = w1[k * 80 + 64 + j];
    }
    if (threadIdx.x < 64) al[threadIdx.x] = attl[threadIdx.x];
    __syncthreads();
    int e = blockIdx.x * blockDim.x + threadIdx.x;
    if (e >= E) return;
    int s = src[e], d = dstv[e];
    float acc[64];
    const float* nr = np1 + (size_t)s * 64;
    #pragma unroll
    for (int k = 0; k < 64; k += 4){
        float4 t = *(const float4*)(nr + k);
        acc[k] = t.x; acc[k+1] = t.y; acc[k+2] = t.z; acc[k+3] = t.w;
    }
    #pragma unroll
    for (int k = 0; k < 64; ++k) PIN(acc[k]);
    const float* er = ea + (size_t)e * 16;
    #pragma unroll
    for (int j = 0; j < 16; ++j){
        float v = er[j];
        #pragma unroll
        for (int k = 0; k < 64; k += 4){
            float4 t = *(const float4*)&wlds[j * 64 + k];
            acc[k]   = fmaf(v, t.x, acc[k]);
            acc[k+1] = fmaf(v, t.y, acc[k+1]);
            acc[k+2] = fmaf(v, t.z, acc[k+2]);
            acc[k+3] = fmaf(v, t.w, acc[k+3]);
        }
    }
    float l = 0.f;
    #pragma unroll
    for (int k = 0; k < 64; ++k) l = fmaf(lrelu01(acc[k]), al[k], l);
    logitC[slot[e]] = lrelu01(l + nat[d]);
}

// GATE aggregate: linear CSR reads, 4-way unrolled row gathers
__global__ __launch_bounds__(THREADS, 8)
void k_gate_agg(const float* __restrict__ logitC, const int* __restrict__ srcC,
                const int* __restrict__ rowptr,
                const float* __restrict__ xg, const float* __restrict__ bias,
                float* __restrict__ xin, int N){
    const int lane = threadIdx.x & 63;
    const int d = blockIdx.x * (blockDim.x >> 6) + (threadIdx.x >> 6);
    if (d >= N) return;
    int r0 = rowptr[d], r1 = rowptr[d + 1];
    float m = -3.4e38f;
    for (int j = r0 + lane; j < r1; j += 64) m = fmaxf(m, logitC[j]);
    m = wmaxf(m);
    float s0 = 0.f, s1 = 0.f, s2 = 0.f, s3 = 0.f;
    float h0 = 0.f, h1 = 0.f, h2 = 0.f, h3 = 0.f;
    int j = r0;
    for (; j + 3 < r1; j += 4){
        float l0 = logitC[j], l1 = logitC[j+1], l2 = logitC[j+2], l3 = logitC[j+3];
        int n0 = srcC[j], n1 = srcC[j+1], n2 = srcC[j+2], n3 = srcC[j+3];
        float w0 = __expf(l0 - m), w1 = __expf(l1 - m);
        float w2 = __expf(l2 - m), w3 = __expf(l3 - m);
        s0 += w0; s1 += w1; s2 += w2; s3 += w3;
        h0 = fmaf(w0, xg[(size_t)n0 * 64 + lane], h0);
        h1 = fmaf(w1, xg[(size_t)n1 * 64 + lane], h1);
        h2 = fmaf(w2, xg[(size_t)n2 * 64 + lane], h2);
        h3 = fmaf(w3, xg[(size_t)n3 * 64 + lane], h3);
    }
    for (; j < r1; ++j){
        float w0 = __expf(logitC[j] - m);
        s0 += w0;
        h0 = fmaf(w0, xg[(size_t)srcC[j] * 64 + lane], h0);
    }
    float s = (s0 + s1) + (s2 + s3);
    float hk = (h0 + h1) + (h2 + h3);
    float h = hk / (s + 1e-16f) + bias[lane];
    xin[(size_t)d * 64 + lane] = eluf(h);
}

// GAT aggregate: logits inline from asrc[srcC[j]]+adst[d], 4-way unrolled
__global__ __launch_bounds__(THREADS, 8)
void k_atom_agg(const float* __restrict__ asrc, const float* __restrict__ adst,
                const int* __restrict__ srcC, const int* __restrict__ rowptr,
                const float* __restrict__ xl,
                const float* __restrict__ bias, float* __restrict__ xin, int N){
    const int lane = threadIdx.x & 63;
    const int d = blockIdx.x * (blockDim.x >> 6) + (threadIdx.x >> 6);
    if (d >= N) return;
    int r0 = rowptr[d], r1 = rowptr[d + 1];
    const float ad = adst[d];
    float m = -3.4e38f;
    for (int j = r0 + lane; j < r1; j += 64)
        m = fmaxf(m, lrelu01(asrc[srcC[j]] + ad));
    m = wmaxf(m);
    float s0 = 0.f, s1 = 0.f, s2 = 0.f, s3 = 0.f;
    float h0 = 0.f, h1 = 0.f, h2 = 0.f, h3 = 0.f;
    int j = r0;
    for (; j + 3 < r1; j += 4){
        int n0 = srcC[j], n1 = srcC[j+1], n2 = srcC[j+2], n3 = srcC[j+3];
        float w0 = __expf(lrelu01(asrc[n0] + ad) - m);
        float w1 = __expf(lrelu01(asrc[n1] + ad) - m);
        float w2 = __expf(lrelu01(asrc[n2] + ad) - m);
        float w3 = __expf(lrelu01(asrc[n3] + ad) - m);
        s0 += w0; s1 += w1; s2 += w2; s3 += w3;
        h0 = fmaf(w0, xl[(size_t)n0 * 64 + lane], h0);
        h1 = fmaf(w1, xl[(size_t)n1 * 64 + lane], h1);
        h2 = fmaf(w2, xl[(size_t)n2 * 64 + lane], h2);
        h3 = fmaf(w3, xl[(size_t)n3 * 64 + lane], h3);
    }
    for (; j < r1; ++j){
        int n0 = srcC[j];
        float w0 = __expf(lrelu01(asrc[n0] + ad) - m);
        s0 += w0;
        h0 = fmaf(w0, xl[(size_t)n0 * 64 + lane], h0);
    }
    float s = (s0 + s1) + (s2 + s3);
    float hk = (h0 + h1) + (h2 + h3);
    float h = hk / (s + 1e-16f) + bias[lane];
    xin[(size_t)d * 64 + lane] = eluf(h);
}

// out0[b] = relu(sum over nodes of graph b)
__global__ __launch_bounds__(THREADS, 4)
void k_out0(const float* __restrict__ x, const int* __restrict__ rpB,
            float* __restrict__ outB, int B){
    const int lane = threadIdx.x & 63;
    const int b = blockIdx.x * (blockDim.x >> 6) + (threadIdx.x >> 6);
    if (b >= B) return;
    int r0 = rpB[b], r1 = rpB[b + 1];
    float a = 0.f;
    for (int n = r0; n < r1; ++n) a += x[(size_t)n * 64 + lane];
    outB[(size_t)b * 64 + lane] = reluf(a);
}

// readout attention step
__global__ __launch_bounds__(THREADS, 2)
void k_mol_attn(const float* __restrict__ outB, const float* __restrict__ W,
                const float* __restrict__ attdst, const float* __restrict__ a_src,
                const float* __restrict__ xs, const int* __restrict__ rpB,
                const float* __restrict__ bias, float* __restrict__ hB, int B){
    const int lane = threadIdx.x & 63;
    const int b = blockIdx.x * (blockDim.x >> 6) + (threadIdx.x >> 6);
    if (b >= B) return;
    float w[64];
    #pragma unroll
    for (int k = 0; k < 64; k += 4){
        float4 t = *(const float4*)(W + (size_t)lane * 64 + k);
        w[k] = t.x; w[k+1] = t.y; w[k+2] = t.z; w[k+3] = t.w;
    }
    const float* orow = outB + (size_t)b * 64;
    float acc = 0.f;
    #pragma unroll
    for (int k = 0; k < 64; ++k) acc = fmaf(orow[k], w[k], acc);
    float g = wsumf(acc * attdst[lane]);
    int r0 = rpB[b], r1 = rpB[b + 1];
    float m = -3.4e38f;
    for (int n = r0 + lane; n < r1; n += 64) m = fmaxf(m, lrelu01(a_src[n] + g));
    m = wmaxf(m);
    float s = 0.f, hk = 0.f;
    for (int n = r0; n < r1; ++n){
        float l = lrelu01(a_src[n] + g);
        float ww = __expf(l - m);
        s += ww;
        hk = fmaf(ww, xs[(size_t)n * 64 + lane], hk);
    }
    hB[(size_t)b * 64 + lane] = eluf(hk / (s + 1e-16f) + bias[lane]);
}

// regression head
__global__ void k_head(const float* __restrict__ emb, const float* __restrict__ lng,
                       const float* __restrict__ lnb,
                       const float* __restrict__ w1, const float* __restrict__ b1,
                       const float* __restrict__ w2, const float* __restrict__ b2,
                       const float* __restrict__ w3, const float* __restrict__ b3,
                       float* __restrict__ out, int B, int P){
    __shared__ float w1t[4096], w2t[4096];
    __shared__ float buf0[4][64], buf1[4][64];
    for (int i = threadIdx.x; i < 4096; i += blockDim.x){
        int h = i >> 6, k = i & 63;
        w1t[k * 64 + h] = w1[i];
        w2t[k * 64 + h] = w2[i];
    }
    __syncthreads();
    const int lane = threadIdx.x & 63;
    const int wv = threadIdx.x >> 6;
    int b = blockIdx.x * (blockDim.x >> 6) + wv;
    bool act = b < B;
    float v = act ? emb[(size_t)b * 64 + lane] : 0.f;
    float mean = wsumf(v) * 0.015625f;
    float dv = v - mean;
    float var = wsumf(dv * dv) * 0.015625f;
    float y = dv * rsqrtf(var + 1e-5f) * lng[lane] + lnb[lane];
    buf0[wv][lane] = y;
    __syncthreads();
    float a1 = b1[lane];
    #pragma unroll
    for (int k = 0; k < 64; ++k) a1 = fmaf(buf0[wv][k], w1t[k * 64 + lane], a1);
    float y1 = reluf(a1);
    buf1[wv][lane] = y1;
    __syncthreads();
    float a2 = b2[lane];
    #pragma unroll
    for (int k = 0; k < 64; ++k) a2 = fmaf(buf1[wv][k], w2t[k * 64 + lane], a2);
    float y2 = reluf(a2);
    for (int p = 0; p < P; ++p){
        float s = wsumf(y2 * w3[p * 64 + lane]);
        if (lane == 0 && act) out[(size_t)b * P + p] = s + b3[p];
    }
}

extern "C" void kernel_launch(void* const* d_in, const int* in_sizes, int n_in,
                              void* d_out, int out_size, void* d_ws, size_t ws_size,
                              hipStream_t stream){
    const float* x       = (const float*)d_in[0];
    const float* eattr   = (const float*)d_in[1];
    const float* lin1_w  = (const float*)d_in[2];
    const float* lin1_b  = (const float*)d_in[3];
    const float* g_l1w   = (const float*)d_in[4];
    const float* g_l2w   = (const float*)d_in[5];
    const float* g_attl  = (const float*)d_in[6];
    const float* g_attr  = (const float*)d_in[7];
    const float* g_bias  = (const float*)d_in[8];
    const float* gru0_wx = (const float*)d_in[9];
    const float* gru0_wh = (const float*)d_in[10];
    const float* gru0_bx = (const float*)d_in[11];
    const float* gru0_bh = (const float*)d_in[12];
    const float* a_linw  = (const float*)d_in[13];
    const float* a_asrc  = (const float*)d_in[14];
    const float* a_adst  = (const float*)d_in[15];
    const float* a_bias  = (const float*)d_in[16];
    const float* a_gwx   = (const float*)d_in[17];
    const float* a_gwh   = (const float*)d_in[18];
    const float* a_gbx   = (const float*)d_in[19];
    const float* a_gbh   = (const float*)d_in[20];
    const float* m_linw  = (const float*)d_in[21];
    const float* m_asrcv = (const float*)d_in[22];
    const float* m_adstv = (const float*)d_in[23];
    const float* m_bias  = (const float*)d_in[24];
    const float* m_gwx   = (const float*)d_in[25];
    const float* m_gwh   = (const float*)d_in[26];
    const float* m_gbx   = (const float*)d_in[27];
    const float* m_gbh   = (const float*)d_in[28];
    const float* lin2_w  = (const float*)d_in[29];
    const float* lin2_b  = (const float*)d_in[30];
    const float* ln_g    = (const float*)d_in[31];
    const float* ln_b    = (const float*)d_in[32];
    const float* h1_w    = (const float*)d_in[33];
    const float* h1_b    = (const float*)d_in[34];
    const float* h2_w    = (const float*)d_in[35];
    const float* h2_b    = (const float*)d_in[36];
    const float* h3_w    = (const float*)d_in[37];
    const float* h3_b    = (const float*)d_in[38];
    const int*   ei      = (const int*)d_in[39];
    const int*   batch   = (const int*)d_in[40];
    float* out = (float*)d_out;

    const int N = in_sizes[0] / 64;
    const int E = in_sizes[1] / 16;
    const int P = in_sizes[38];
    const int B = out_size / (P > 0 ? P : 1);
    const int* srcv = ei;
    const int* dstv = ei + E;

    // ---- workspace layout ----
    float* Wb = (float*)d_ws;
    size_t nb = (size_t)N * 64;
    size_t bb = (size_t)B * 64;
    float* P0 = Wb;
    float* P1 = P0 + nb;
    float* P2 = P1 + nb;
    float* P3 = P2 + nb;
    float* P4 = P3 + nb;
    float* P5 = P4 + nb;
    float* logitC = P5 + nb;
    float* scal  = logitC + E;
    float* outB0 = scal + 2 * (size_t)N;
    float* outB1 = outB0 + bb;
    float* hB    = outB1 + bb;
    float* RB    = hB + bb;
    float* ZB    = RB + bb;
    float* XNB   = ZB + bb;
    int* srcC   = (int*)(XNB + bb);
    int* slot   = srcC + E;
    int* rowptr = slot + E;
    int* cnt    = rowptr + (N + 1);
    int* cnt2   = cnt + N;
    int* rpB    = cnt2 + N;
    int* bsum   = rpB + (B + 1);
    const int NB = (N + 1023) >> 10;
    size_t need = (size_t)((char*)(bsum + NB) - (char*)d_ws);
    if (need > ws_size) return;
    float* embB = XNB;

    dim3 blk(THREADS);
    int gE    = (E + THREADS - 1) / THREADS;
    int gN4   = (N + 3) / 4;
    int gB4   = (B + 3) / 4;
    int gN256 = (N + THREADS - 1) / THREADS;
    int ntN   = (N + 63) >> 6;
    int ntB   = (B + 63) >> 6;
    int GT_N  = ntN < 768 ? ntN : 768;   // 3 blocks/CU tile kernels
    int GT_N2 = ntN < 512 ? ntN : 512;   // 2 blocks/CU (high-VGPR fused kernels)
    int GT_B  = ntB;

    // ---- CSR build ----
    hipMemsetAsync(cnt, 0, sizeof(int) * 2 * (size_t)N, stream);
    k_hist<<<gE, blk, 0, stream>>>(dstv, cnt, E);
    k_scan1<<<NB, 1024, 0, stream>>>(cnt, rowptr, bsum, N);
    k_scan2<<<1, 1024, 0, stream>>>(bsum, rowptr, NB, N);
    k_scan3<<<NB, 1024, 0, stream>>>(rowptr, bsum, N);
    k_scatter<<<gE, blk, 0, stream>>>(dstv, srcv, rowptr, cnt2, srcC, slot, E);
    k_browptr<<<gN256, blk, 0, stream>>>(batch, rpB, N, B);

    // ---- phase 0: x1 = lrelu(x@lin1+b) -> P0, fused nat -> scal ----
    k_mm64t<1,1><<<GT_N, blk, 0, stream>>>(x, lin1_w, 64, lin1_b, P0,
                                           g_attr, nullptr, scal, nullptr, N);

    // ---- GATEConv ----
    k_mm64_x2<<<GT_N2, blk, 0, stream>>>(P0, g_l1w, 80, g_l2w, 64, P1, P2, N); // np1, xg
    k_gate_logit<<<gE, blk, 0, stream>>>(P1, eattr, g_l1w, g_attl, scal, srcv, dstv,
                                         slot, logitC, E);
    k_gate_agg<<<gN4, blk, 0, stream>>>(logitC, srcC, rowptr, P2, g_bias, P3, N);
    // GRU0: xin=P3, xp=P0 -> x=P1. T: Tr=P2, Tz=P5, Tn=P4
    k_gru_wx3<<<GT_N2, blk, 0, stream>>>(P3, gru0_wx, gru0_bx, P2, P5, P4, N);
    k_gru_whf<<<GT_N2, blk, 0, stream>>>(P0, gru0_wh, gru0_bh, P2, P5, P4, P1, N);

    // ---- atom layer 0: x=P1 -> x=P4. T: Tr=P0, Tz=P2, Tn=P5 ----
    k_mm64t<0,2><<<GT_N, blk, 0, stream>>>(P1, a_linw, 64, nullptr, P0,
                                           a_asrc, a_adst, scal, scal + N, N);
    k_atom_agg<<<gN4, blk, 0, stream>>>(scal, scal + N, srcC, rowptr, P0, a_bias, P3, N);
    k_gru_wx3<<<GT_N2, blk, 0, stream>>>(P3, a_gwx, a_gbx, P0, P2, P5, N);
    k_gru_whf<<<GT_N2, blk, 0, stream>>>(P1, a_gwh, a_gbh, P0, P2, P5, P4, N);

    // ---- atom layer 1: x=P4 -> x=P1. T: Tr=P0, Tz=P2, Tn=P5 ----
    k_mm64t<0,2><<<GT_N, blk, 0, stream>>>(P4, a_linw + 4096, 64, nullptr, P0,
                                           a_asrc + 64, a_adst + 64, scal, scal + N, N);
    k_atom_agg<<<gN4, blk, 0, stream>>>(scal, scal + N, srcC, rowptr, P0, a_bias + 64, P3, N);
    k_gru_wx3<<<GT_N2, blk, 0, stream>>>(P3, a_gwx + 12288, a_gbx + 192, P0, P2, P5, N);
    k_gru_whf<<<GT_N2, blk, 0, stream>>>(P4, a_gwh + 12288, a_gbh + 192, P0, P2, P5, P1, N);

    // ---- readout: x=P1 ----
    k_mm64t<0,1><<<GT_N, blk, 0, stream>>>(P1, m_linw, 64, nullptr, P0,
                                           m_asrcv, nullptr, scal, nullptr, N); // xs + a_src
    k_out0<<<gB4, blk, 0, stream>>>(P1, rpB, outB0, B);
    float* cur = outB0;
    float* nxt = outB1;
    for (int t = 0; t < 3; ++t){
        k_mol_attn<<<gB4, blk, 0, stream>>>(cur, m_linw, m_adstv, scal, P0, rpB, m_bias, hB, B);
        k_gru_wx3<<<GT_B, blk, 0, stream>>>(hB, m_gwx, m_gbx, RB, ZB, XNB, B);
        k_gru_whf<<<GT_B, blk, 0, stream>>>(cur, m_gwh, m_gbh, RB, ZB, XNB, nxt, B);
        float* tmp = cur; cur = nxt; nxt = tmp;
    }

    // ---- head ----
    k_mm64t<0,0><<<GT_B, blk, 0, stream>>>(cur, lin2_w, 64, lin2_b, embB,
                                           nullptr, nullptr, nullptr, nullptr, B);
    k_head<<<gB4, blk, 0, stream>>>(embB, ln_g, ln_b, h1_w, h1_b, h2_w, h2_b, h3_w, h3_b, out, B, P);
}